// Round 14
// baseline (1017.042 us; speedup 1.0000x reference)
//
#include <hip/hip_runtime.h>
#include <hip/hip_bf16.h>
#include <math.h>

#define B_  64
#define A_  26
#define L_  384
#define D_  512
#define K_  18
#define KC  480      // im2col K padded (468 -> 480, multiple of 32)
#define LL  147456   // L_*L_
#define SZD 245760   // per-batch diagonal-layout stride: 160 diags x 1536 floats

typedef __attribute__((ext_vector_type(8))) short bf16x8;   // 8 bf16 = 4 VGPRs
typedef __attribute__((ext_vector_type(4))) float f32x4;
typedef unsigned short ushort_t;
typedef unsigned int uint_t;

// Diagonal layout: element (row z, col c), l=z/6, r=z%6, ct=c/4:
//   addr = (l+ct)*1536 + r*256 + l*4 + (c&3);  d=l+ct lane-invariant per body -> dense.
__device__ __forceinline__ void stD(float* sp, int z, int c, float v) {
    int dl = z / 6, dr = z - dl * 6;
    sp[(size_t)(dl + (c >> 2)) * 1536 + dr * 256 + dl * 4 + (c & 3)] = v;
}

// RNE f32 -> bf16 bits
__device__ __forceinline__ ushort_t f2bf(float v) {
    uint_t u = __float_as_uint(v);
    uint_t r = (u + 0x7FFFu + ((u >> 16) & 1u)) >> 16;
    return (ushort_t)r;
}

// ---------------- weight split: conv_w (D, A*K) -> wcol hi/lo (D, KC) ----------------
__global__ void wsplit_kernel(const float* __restrict__ w, ushort_t* __restrict__ wh,
                              ushort_t* __restrict__ wl) {
    int o = blockIdx.x * blockDim.x + threadIdx.x;   // o = d*KC + r
    if (o >= D_ * KC) return;
    int d = o / KC, r = o - d * KC;
    float v = (r < A_ * K_) ? w[(size_t)d * (A_ * K_) + r] : 0.0f;
    ushort_t h = f2bf(v);
    float hf = __uint_as_float(((uint_t)h) << 16);
    wh[o] = h;
    wl[o] = f2bf(v - hf);
}

// ---------------- im2col: x (B,A,L) -> xcol hi/lo (B, L, KC) ----------------
// xcol[b][l][a*18+kk] = x[b][a][l+kk-8] (0 outside), r in [468,480) = 0.
__global__ __launch_bounds__(256) void im2col_kernel(const float* __restrict__ x,
                                                     ushort_t* __restrict__ xh,
                                                     ushort_t* __restrict__ xl) {
    int b  = blockIdx.y;
    int lt = blockIdx.x;                 // 0..5, 64 l's each
    const float* xb = x + (size_t)b * A_ * L_;
    for (int idx = threadIdx.x; idx < 64 * KC; idx += 256) {
        int l = lt * 64 + idx / KC;
        int r = idx % KC;
        float v = 0.0f;
        if (r < A_ * K_) {
            int a = r / K_, kk = r - a * K_;
            int g = l + kk - 8;
            if (g >= 0 && g < L_) v = xb[(size_t)a * L_ + g];
        }
        ushort_t h = f2bf(v);
        float hf = __uint_as_float(((uint_t)h) << 16);
        size_t o = ((size_t)b * L_ + l) * KC + r;
        xh[o] = h;
        xl[o] = f2bf(v - hf);
    }
}

// ---------------- conv as split-bf16 MFMA GEMM: e = xcol @ wcol^T + bias ----------------
// M=L(l), N=D(d), K=KC. Same structure as sim_kernel. Epilogue splits to ehi/elo.
__global__ __launch_bounds__(256) void convmm_kernel(const ushort_t* __restrict__ xh,
                                                     const ushort_t* __restrict__ xl,
                                                     const ushort_t* __restrict__ wh,
                                                     const ushort_t* __restrict__ wl,
                                                     const float* __restrict__ bias,
                                                     ushort_t* __restrict__ ehi,
                                                     ushort_t* __restrict__ elo) {
    int b = blockIdx.z;
    int w = threadIdx.x >> 6;
    int lane = threadIdx.x & 63;
    int l0 = blockIdx.y * 64 + 32 * (w >> 1);
    int d0 = blockIdx.x * 64 + 32 * (w & 1);
    int r = lane & 15, g = lane >> 4;
    const ushort_t* pah = xh + ((size_t)b * L_ + l0 + r) * KC + g * 8;
    const ushort_t* pal = xl + ((size_t)b * L_ + l0 + r) * KC + g * 8;
    const ushort_t* pbh = wh + (size_t)(d0 + r) * KC + g * 8;
    const ushort_t* pbl = wl + (size_t)(d0 + r) * KC + g * 8;
    f32x4 acc00 = {0.f, 0.f, 0.f, 0.f}, acc01 = acc00, acc10 = acc00, acc11 = acc00;
#pragma unroll 3
    for (int ks = 0; ks < 15; ++ks) {
        int off = ks * 32;
        bf16x8 Ah0 = *(const bf16x8*)(pah + off);
        bf16x8 Ah1 = *(const bf16x8*)(pah + 16 * KC + off);
        bf16x8 Al0 = *(const bf16x8*)(pal + off);
        bf16x8 Al1 = *(const bf16x8*)(pal + 16 * KC + off);
        bf16x8 Bh0 = *(const bf16x8*)(pbh + off);
        bf16x8 Bh1 = *(const bf16x8*)(pbh + 16 * KC + off);
        bf16x8 Bl0 = *(const bf16x8*)(pbl + off);
        bf16x8 Bl1 = *(const bf16x8*)(pbl + 16 * KC + off);
        acc00 = __builtin_amdgcn_mfma_f32_16x16x32_bf16(Ah0, Bh0, acc00, 0, 0, 0);
        acc00 = __builtin_amdgcn_mfma_f32_16x16x32_bf16(Ah0, Bl0, acc00, 0, 0, 0);
        acc00 = __builtin_amdgcn_mfma_f32_16x16x32_bf16(Al0, Bh0, acc00, 0, 0, 0);
        acc01 = __builtin_amdgcn_mfma_f32_16x16x32_bf16(Ah0, Bh1, acc01, 0, 0, 0);
        acc01 = __builtin_amdgcn_mfma_f32_16x16x32_bf16(Ah0, Bl1, acc01, 0, 0, 0);
        acc01 = __builtin_amdgcn_mfma_f32_16x16x32_bf16(Al0, Bh1, acc01, 0, 0, 0);
        acc10 = __builtin_amdgcn_mfma_f32_16x16x32_bf16(Ah1, Bh0, acc10, 0, 0, 0);
        acc10 = __builtin_amdgcn_mfma_f32_16x16x32_bf16(Ah1, Bl0, acc10, 0, 0, 0);
        acc10 = __builtin_amdgcn_mfma_f32_16x16x32_bf16(Al1, Bh0, acc10, 0, 0, 0);
        acc11 = __builtin_amdgcn_mfma_f32_16x16x32_bf16(Ah1, Bh1, acc11, 0, 0, 0);
        acc11 = __builtin_amdgcn_mfma_f32_16x16x32_bf16(Ah1, Bl1, acc11, 0, 0, 0);
        acc11 = __builtin_amdgcn_mfma_f32_16x16x32_bf16(Al1, Bh1, acc11, 0, 0, 0);
    }
#pragma unroll
    for (int v = 0; v < 4; ++v) {
        int lr0 = l0 + g * 4 + v, lr1 = lr0 + 16;
        int dc0 = d0 + r,         dc1 = dc0 + 16;
        float vals[4] = {acc00[v] + bias[dc0], acc01[v] + bias[dc1],
                         acc10[v] + bias[dc0], acc11[v] + bias[dc1]};
        int lrs[4] = {lr0, lr0, lr1, lr1};
        int dcs[4] = {dc0, dc1, dc0, dc1};
#pragma unroll
        for (int t = 0; t < 4; ++t) {
            ushort_t h = f2bf(vals[t]);
            float hf = __uint_as_float(((uint_t)h) << 16);
            size_t o = ((size_t)b * L_ + lrs[t]) * D_ + dcs[t];
            ehi[o] = h;
            elo[o] = f2bf(vals[t] - hf);
        }
    }
}

// ---------------- sim = E_b · E_0^T via split-bf16 MFMA; writes diagonal layout ----------------
__global__ __launch_bounds__(256) void sim_kernel(const ushort_t* __restrict__ ehi,
                                                  const ushort_t* __restrict__ elo,
                                                  float* __restrict__ simD) {
    int b = blockIdx.z;
    int w = threadIdx.x >> 6;
    int lane = threadIdx.x & 63;
    int l0 = blockIdx.y * 64 + 32 * (w >> 1);
    int m0 = blockIdx.x * 64 + 32 * (w & 1);
    int r = lane & 15, g = lane >> 4;
    size_t rowA = ((size_t)b * L_ + l0 + r) * D_ + g * 8;
    size_t rowB = ((size_t)m0 + r) * D_ + g * 8;      // batch 0
    const ushort_t* pah = ehi + rowA;
    const ushort_t* pal = elo + rowA;
    const ushort_t* pbh = ehi + rowB;
    const ushort_t* pbl = elo + rowB;
    f32x4 acc00 = {0.f, 0.f, 0.f, 0.f}, acc01 = acc00, acc10 = acc00, acc11 = acc00;
#pragma unroll 2
    for (int ks = 0; ks < 16; ++ks) {
        int off = ks * 32;
        bf16x8 Ah0 = *(const bf16x8*)(pah + off);
        bf16x8 Ah1 = *(const bf16x8*)(pah + 16 * D_ + off);
        bf16x8 Al0 = *(const bf16x8*)(pal + off);
        bf16x8 Al1 = *(const bf16x8*)(pal + 16 * D_ + off);
        bf16x8 Bh0 = *(const bf16x8*)(pbh + off);
        bf16x8 Bh1 = *(const bf16x8*)(pbh + 16 * D_ + off);
        bf16x8 Bl0 = *(const bf16x8*)(pbl + off);
        bf16x8 Bl1 = *(const bf16x8*)(pbl + 16 * D_ + off);
        acc00 = __builtin_amdgcn_mfma_f32_16x16x32_bf16(Ah0, Bh0, acc00, 0, 0, 0);
        acc00 = __builtin_amdgcn_mfma_f32_16x16x32_bf16(Ah0, Bl0, acc00, 0, 0, 0);
        acc00 = __builtin_amdgcn_mfma_f32_16x16x32_bf16(Al0, Bh0, acc00, 0, 0, 0);
        acc01 = __builtin_amdgcn_mfma_f32_16x16x32_bf16(Ah0, Bh1, acc01, 0, 0, 0);
        acc01 = __builtin_amdgcn_mfma_f32_16x16x32_bf16(Ah0, Bl1, acc01, 0, 0, 0);
        acc01 = __builtin_amdgcn_mfma_f32_16x16x32_bf16(Al0, Bh1, acc01, 0, 0, 0);
        acc10 = __builtin_amdgcn_mfma_f32_16x16x32_bf16(Ah1, Bh0, acc10, 0, 0, 0);
        acc10 = __builtin_amdgcn_mfma_f32_16x16x32_bf16(Ah1, Bl0, acc10, 0, 0, 0);
        acc10 = __builtin_amdgcn_mfma_f32_16x16x32_bf16(Al1, Bh0, acc10, 0, 0, 0);
        acc11 = __builtin_amdgcn_mfma_f32_16x16x32_bf16(Ah1, Bh1, acc11, 0, 0, 0);
        acc11 = __builtin_amdgcn_mfma_f32_16x16x32_bf16(Ah1, Bl1, acc11, 0, 0, 0);
        acc11 = __builtin_amdgcn_mfma_f32_16x16x32_bf16(Al1, Bh1, acc11, 0, 0, 0);
    }
    float* sp = simD + (size_t)b * SZD;
#pragma unroll
    for (int v = 0; v < 4; ++v) {
        int ar0 = l0 + g * 4 + v, ar1 = ar0 + 16;
        int ac0 = m0 + r,         ac1 = ac0 + 16;
        stD(sp, ar0, ac0, acc00[v]);
        stD(sp, ar0, ac1, acc01[v]);
        stD(sp, ar1, ac0, acc10[v]);
        stD(sp, ar1, ac1, acc11[v]);
    }
}

// ---------------- NW forward: 4-wave round-robin body pipeline, mailbox handoff ----------------
__global__ __launch_bounds__(256, 1) void nw_fwd_kernel(const float* __restrict__ simD, float* __restrict__ VD) {
    int b = blockIdx.x;
    int tid = threadIdx.x;
    int w = tid >> 6, l = tid & 63;
    __shared__ float4 MA[4][64], MB4[4][64], MC[4][64];
    __shared__ int FL[4];
    const float4 Z4 = {0.f, 0.f, 0.f, 0.f};
    for (int k = tid; k < 256; k += 256) {
        int s = k >> 6, ll = k & 63;
        MA[s][ll] = Z4; MB4[s][ll] = Z4; MC[s][ll] = Z4;
    }
    if (tid < 4) FL[tid] = (tid == 3) ? -1 : -1000000;
    __syncthreads();
    volatile int* flg = FL;
    const float* pS = simD + (size_t)b * SZD + l * 4;
    float*       pV = VD   + (size_t)b * SZD + l * 4;
    float4 buf[6];
#pragma unroll
    for (int r = 0; r < 6; ++r) buf[r] = *(const float4*)(pS + w * 1536 + r * 256);
    int lm = (l == 0) ? 0 : (l - 1);
#pragma unroll 1
    for (int T = w; T < 159; T += 4) {
        int sp = (T - 1) & 3;
        while (flg[sp] != T - 1) {}
        asm volatile("" ::: "memory");
        float4 Ar = MA[sp][l];
        float4 Bs = MB4[sp][l];
        float4 Cs = MC[sp][l];
        float4 Bn = MB4[sp][lm];
        float4 Cn = MC[sp][lm];
        if (l == 0) { Bn = Z4; Cn = Z4; }
        float vleft[6] = {Ar.x, Ar.y, Ar.z, Ar.w, Bs.x, Bs.y};
        float d0 = Bn.z;                              // V[6l, c0]
        float uin[4] = {Cn.x, Cn.y, Cn.z, Cn.w};      // V[6l, c0+q+1]
        float sc[6][4];
#pragma unroll
        for (int r = 0; r < 6; ++r) {
            sc[r][0] = buf[r].x; sc[r][1] = buf[r].y; sc[r][2] = buf[r].z; sc[r][3] = buf[r].w;
        }
        int dP = min(T + 4, 158);                     // next body's tile
#pragma unroll
        for (int r = 0; r < 6; ++r) buf[r] = *(const float4*)(pS + dP * 1536 + r * 256);
        int ct = T - l;
        float nbc[4] = {0.f, 0.f, 0.f, 0.f}, nbp = 0.f;
        if (ct >= 0 && ct <= 95) {
            float vout[6][4];
#pragma unroll
            for (int q = 0; q < 4; ++q) {
                float dg = (q == 0) ? d0 : uin[q - 1];
                float up = uin[q];
#pragma unroll
                for (int r = 0; r < 6; ++r) {
                    float lf = vleft[r];
                    float mx = fmaxf(dg, fmaxf(up, lf));
                    float v = sc[r][q] + mx + __logf(__expf(dg - mx) + __expf(up - mx) + __expf(lf - mx));
                    dg = lf; up = v;
                    vleft[r] = v;
                    vout[r][q] = v;
                }
            }
            nbp = Cs.w;                               // own old bcarry[3] = V[6l+6, 4ct]
#pragma unroll
            for (int q = 0; q < 4; ++q) nbc[q] = vout[5][q];
            float* pVd = pV + (size_t)T * 1536;
#pragma unroll
            for (int r = 0; r < 6; ++r) {
                float4 t;
                t.x = vout[r][0]; t.y = vout[r][1]; t.z = vout[r][2]; t.w = vout[r][3];
                *(float4*)(pVd + r * 256) = t;
            }
        }
        float4 pa; pa.x = vleft[0]; pa.y = vleft[1]; pa.z = vleft[2]; pa.w = vleft[3];
        float4 pb; pb.x = vleft[4]; pb.y = vleft[5]; pb.z = nbp; pb.w = 0.f;
        float4 pc; pc.x = nbc[0]; pc.y = nbc[1]; pc.z = nbc[2]; pc.w = nbc[3];
        MA[w][l] = pa; MB4[w][l] = pb; MC[w][l] = pc;
        asm volatile("s_waitcnt lgkmcnt(0)" ::: "memory");
        if (l == 0) flg[w] = T;
    }
}

// ---------------- NW backward: 4-wave round-robin body pipeline, mailbox handoff ----------------
__global__ __launch_bounds__(256, 1) void nw_bwd_kernel(const float* __restrict__ simD,
                                                        const float* __restrict__ VD,
                                                        const int* __restrict__ shapes,
                                                        float* __restrict__ ED) {
    int b = blockIdx.x;
    int tid = threadIdx.x;
    int w = tid >> 6, l = tid & 63;
    __shared__ float4 MA[4][64], MB4[4][64], MC[4][64], MD[4][64], MEx[4][64], MF[4][64];
    __shared__ int FL[4];
    const float4 Z4 = {0.f, 0.f, 0.f, 0.f};
    for (int k = tid; k < 256; k += 256) {
        int s = k >> 6, ll = k & 63;
        MA[s][ll] = Z4; MB4[s][ll] = Z4; MC[s][ll] = Z4;
        MD[s][ll] = Z4; MEx[s][ll] = Z4; MF[s][ll] = Z4;
    }
    if (tid < 4) FL[tid] = (tid == 3) ? -1 : -1000000;
    __syncthreads();
    volatile int* flg = FL;
    const float* pS = simD + (size_t)b * SZD + l * 4;
    const float* pV = VD   + (size_t)b * SZD + l * 4;
    float*       pE = ED   + (size_t)b * SZD + l * 4;
    int li = min(max(shapes[2 * b + 0], 0), L_);
    int lj = min(max(shapes[2 * b + 1], 0), L_);
    float4 bufV[6], bufS[6];
#pragma unroll
    for (int r = 0; r < 6; ++r) {
        bufV[r] = *(const float4*)(pV + (158 - w) * 1536 + r * 256);
        bufS[r] = *(const float4*)(pS + (158 - w) * 1536 + r * 256);
    }
    int lp = (l == 63) ? 63 : (l + 1);
#pragma unroll 1
    for (int T = w; T < 159; T += 4) {
        int sp = (T - 1) & 3;
        while (flg[sp] != T - 1) {}
        asm volatile("" ::: "memory");
        float4 Ar = MA[sp][l];
        float4 Br = MB4[sp][l];
        float4 Cr = MC[sp][l];
        float4 Dn = MD[sp][lp];
        float4 En = MEx[sp][lp];
        float4 Fn = MF[sp][lp];
        if (l == 63) { Dn = Z4; En = Z4; Fn = Z4; }
        float e[6] = {Ar.x, Ar.y, Ar.z, Ar.w, Br.x, Br.y};
        float u[6] = {Br.z, Br.w, Cr.x, Cr.y, Cr.z, Cr.w};
        float enb_c[4] = {Dn.x, Dn.y, Dn.z, Dn.w};   // E[6l+7, c0+1+q]
        float unb_c[4] = {En.x, En.y, En.z, En.w};   // U[6l+7, c0+1+q]
        float enbtd_s = Fn.x, unbtd_s = Fn.y;        // E/U[6l+7, rightmost+1]
        float e0r = e[0], u0r = u[0];
        float Vq[6][4], Sq[6][4];
#pragma unroll
        for (int r = 0; r < 6; ++r) {
            Vq[r][0] = bufV[r].x; Vq[r][1] = bufV[r].y; Vq[r][2] = bufV[r].z; Vq[r][3] = bufV[r].w;
            Sq[r][0] = bufS[r].x; Sq[r][1] = bufS[r].y; Sq[r][2] = bufS[r].z; Sq[r][3] = bufS[r].w;
        }
        int dP = max(158 - (T + 4), 0);
#pragma unroll
        for (int r = 0; r < 6; ++r) {
            bufV[r] = *(const float4*)(pV + dP * 1536 + r * 256);
            bufS[r] = *(const float4*)(pS + dP * 1536 + r * 256);
        }
        int ct = 158 - T - l;
        float necar[4] = {0.f, 0.f, 0.f, 0.f}, nucar[4] = {0.f, 0.f, 0.f, 0.f};
        if (ct >= 0 && ct <= 95) {
            float Eo[6][4];
#pragma unroll
            for (int qq = 0; qq < 4; ++qq) {
                const int q = 3 - qq;                // descending cols
                int j = 4 * ct + q + 1;
                bool jlt = (j < L_);
                float eo[6], uo[6];
#pragma unroll
                for (int r = 0; r < 6; ++r) { eo[r] = e[r]; uo[r] = u[r]; }
#pragma unroll
                for (int rr = 0; rr < 6; ++rr) {
                    const int r = 5 - rr;            // descending rows
                    int i = 6 * l + r + 1;
                    bool ilt = (i < L_);             // false only l=63, r=5
                    float Vv = Vq[r][q];
                    float u_new = Vv - Sq[r][q];     // U[i, j]
                    float eb_old, ub_old, eb_new, ub_new;
                    if (r == 5) {
                        eb_old = (q == 3) ? enbtd_s : enb_c[q + 1];
                        ub_old = (q == 3) ? unbtd_s : unb_c[q + 1];
                        eb_new = enb_c[q];
                        ub_new = unb_c[q];
                    } else {
                        eb_old = eo[r + 1]; ub_old = uo[r + 1];   // col j+1
                        eb_new = e[r + 1];  ub_new = u[r + 1];    // col j (fresh)
                    }
                    float wtd = (ilt && jlt) ? __expf(Vv - ub_old) : 0.f;
                    float wtu = ilt ? __expf(Vv - ub_new) : 0.f;
                    float wtl = jlt ? __expf(Vv - uo[r]) : 0.f;
                    float en = (i == li && j == lj) ? 1.f : 0.f;
                    en += wtd * eb_old + wtu * eb_new + wtl * eo[r];
                    e[r] = en; u[r] = u_new;
                    Eo[r][q] = en;
                }
            }
#pragma unroll
            for (int q = 0; q < 4; ++q) {
                necar[q] = Eo[0][q];
                nucar[q] = Vq[0][q] - Sq[0][q];
            }
            float* pEd = pE + (size_t)(158 - T) * 1536;
#pragma unroll
            for (int r = 0; r < 6; ++r) {
                float4 t;
                t.x = Eo[r][0]; t.y = Eo[r][1]; t.z = Eo[r][2]; t.w = Eo[r][3];
                *(float4*)(pEd + r * 256) = t;
            }
        }
        float4 pa; pa.x = e[0]; pa.y = e[1]; pa.z = e[2]; pa.w = e[3];
        float4 pb; pb.x = e[4]; pb.y = e[5]; pb.z = u[0]; pb.w = u[1];
        float4 pc; pc.x = u[2]; pc.y = u[3]; pc.z = u[4]; pc.w = u[5];
        float4 pd; pd.x = necar[0]; pd.y = necar[1]; pd.z = necar[2]; pd.w = necar[3];
        float4 pe; pe.x = nucar[0]; pe.y = nucar[1]; pe.z = nucar[2]; pe.w = nucar[3];
        float4 pf; pf.x = e0r; pf.y = u0r; pf.z = 0.f; pf.w = 0.f;
        MA[w][l] = pa; MB4[w][l] = pb; MC[w][l] = pc;
        MD[w][l] = pd; MEx[w][l] = pe; MF[w][l] = pf;
        asm volatile("s_waitcnt lgkmcnt(0)" ::: "memory");
        if (l == 0) flg[w] = T;
    }
}

// ---------------- repack: EDiag (diag layout) -> Enat (B, L, L) row-major ----------------
__global__ __launch_bounds__(256) void repack_kernel(const float* __restrict__ ED,
                                                     float* __restrict__ Enat) {
    int n  = blockIdx.y;
    int jt = blockIdx.x;                 // 0..5
    int jl = threadIdx.x & 63;
    int gp = threadIdx.x >> 6;           // 0..3: i in [gp*96, gp*96+96)
    int j  = jt * 64 + jl;
    const float* eb = ED + (size_t)n * SZD + (j >> 2) * 1536 + (j & 3);
    float* ob = Enat + (size_t)n * LL + j;
#pragma unroll 4
    for (int i = gp * 96; i < gp * 96 + 96; ++i) {
        int dl = i / 6, dr = i - dl * 6;
        float v = eb[(size_t)dl * 1540 + dr * 256];   // dl*1536 + dl*4
        ob[(size_t)i * L_] = v;
    }
}

// ---------------- consensus[j,a] = (1/B) sum_n sum_i matrices[n,a,i]*E[n,i,j] ----------------
__global__ __launch_bounds__(256) void consensus_kernel(const float* __restrict__ x,      // (B,A,L)
                                                        const float* __restrict__ Enat,   // (B,L,L)
                                                        float* __restrict__ cons) {       // (L,A)
    int n  = blockIdx.y;
    int j0 = blockIdx.x * 64;
    __shared__ float ms[A_][L_];    // 39.9 KB: matrices[n] staged
    for (int idx = threadIdx.x; idx < A_ * L_; idx += 256)
        ((float*)ms)[idx] = x[(size_t)n * A_ * L_ + idx];
    __syncthreads();
    int jl = threadIdx.x & 63;
    int g  = threadIdx.x >> 6;      // 0..3
    int a0 = g * 7;                 // 0,7,14,21
    int na = (a0 + 7 <= A_) ? 7 : (A_ - a0);   // 7,7,7,5
    int j  = j0 + jl;
    float acc[7] = {0.f, 0.f, 0.f, 0.f, 0.f, 0.f, 0.f};
    const float* aE = Enat + (size_t)n * LL + j;
    for (int i = 0; i < L_; ++i) {
        float al = aE[(size_t)i * L_];          // 64 consecutive lanes: dense row read
#pragma unroll
        for (int t = 0; t < 7; ++t)
            if (t < na) acc[t] = fmaf(al, ms[a0 + t][i], acc[t]);
    }
    for (int t = 0; t < na; ++t)
        atomicAdd(&cons[(size_t)j * A_ + a0 + t], acc[t] * (1.0f / B_));
}

// ---------------- out[n,i,a] = sum_j cons[j,a] * E[n,i,j] ----------------
__global__ __launch_bounds__(256) void out_kernel(const float* __restrict__ Enat,
                                                  const float* __restrict__ cons,
                                                  float* __restrict__ out) {
    int n  = blockIdx.y;
    int i0 = blockIdx.x * 32;
    __shared__ float cs[L_][A_];        // 40.0 KB
    __shared__ float as_[32][L_ + 1];   // 49.3 KB (pad: break 384-stride bank alias)
    for (int idx = threadIdx.x; idx < L_ * A_; idx += 256)
        ((float*)cs)[idx] = cons[idx];
    const float* aE = Enat + (size_t)n * LL;
    for (int idx = threadIdx.x; idx < 32 * L_; idx += 256) {
        int r = idx / L_, c = idx - r * L_;
        as_[r][c] = aE[(size_t)(i0 + r) * L_ + c];
    }
    __syncthreads();
    for (int o = threadIdx.x; o < 32 * A_; o += 256) {
        int il = o / A_, a = o % A_;
        float s = 0.f;
        for (int jj = 0; jj < L_; ++jj)
            s = fmaf(as_[il][jj], cs[jj][a], s);
        out[((size_t)n * L_ + i0 + il) * A_ + a] = s;
    }
}

extern "C" void kernel_launch(void* const* d_in, const int* in_sizes, int n_in,
                              void* d_out, int out_size, void* d_ws, size_t ws_size,
                              hipStream_t stream) {
    const float* matrices = (const float*)d_in[0];   // (B,A,L) f32
    const int*   shapes   = (const int*)d_in[1];     // (B,2) i32
    const float* conv_w   = (const float*)d_in[2];   // (D,A,K) f32
    const float* conv_b   = (const float*)d_in[3];   // (D,) f32
    float* out = (float*)d_out;                      // (B,L,A) f32

    char* p = (char*)d_ws;
    // region1 (62.9 MB): xcol hi/lo (47.2 MB) during conv; EDiag after bwd (xcol dead).
    float*    EDiag = (float*)p;
    ushort_t* xh = (ushort_t*)p;
    ushort_t* xl = xh + (size_t)B_ * L_ * KC;
    p += (size_t)B_ * SZD * 4;
    // region2 (50.3 MB): ehi/elo (dead after sim_kernel).
    ushort_t* ehi = (ushort_t*)p;
    ushort_t* elo = ehi + (size_t)B_ * L_ * D_;
    p += (size_t)B_ * L_ * D_ * 4;
    // region3 (62.9 MB): simD (dead after bwd) -> Enat (37.7 MB) for repack.
    float* simD = (float*)p;
    float* Enat = simD;
    p += (size_t)B_ * SZD * 4;
    // region4 (62.9 MB): VD.
    float* VD = (float*)p;
    p += (size_t)B_ * SZD * 4;
    ushort_t* wh = (ushort_t*)p;                     // 0.49 MB
    ushort_t* wl = wh + (size_t)D_ * KC;             // 0.49 MB
    p += (size_t)D_ * KC * 4;
    float* cons = (float*)p;                         // 40 KB

    wsplit_kernel<<<(D_ * KC + 255) / 256, 256, 0, stream>>>(conv_w, wh, wl);
    im2col_kernel<<<dim3(L_ / 64, B_), 256, 0, stream>>>(matrices, xh, xl);
    convmm_kernel<<<dim3(D_ / 64, L_ / 64, B_), 256, 0, stream>>>(xh, xl, wh, wl, conv_b, ehi, elo);
    sim_kernel<<<dim3(L_ / 64, L_ / 64, B_), 256, 0, stream>>>(ehi, elo, simD);
    nw_fwd_kernel<<<B_, 256, 0, stream>>>(simD, VD);
    nw_bwd_kernel<<<B_, 256, 0, stream>>>(simD, VD, shapes, EDiag);
    repack_kernel<<<dim3(L_ / 64, B_), 256, 0, stream>>>(EDiag, Enat);
    hipMemsetAsync(cons, 0, (size_t)L_ * A_ * sizeof(float), stream);
    consensus_kernel<<<dim3(L_ / 64, B_), 256, 0, stream>>>(matrices, Enat, cons);
    out_kernel<<<dim3(L_ / 32, B_), 256, 0, stream>>>(Enat, cons, out);
}

// Round 15
// 941.886 us; speedup vs baseline: 1.0798x; 1.0798x over previous
//
#include <hip/hip_runtime.h>
#include <hip/hip_bf16.h>
#include <math.h>

#define B_  64
#define A_  26
#define L_  384
#define D_  512
#define K_  18
#define KC  480      // im2col K padded (468 -> 480, 15 slices of 32)
#define LL  147456   // L_*L_
#define SZD 245760   // per-batch diagonal-layout stride: 160 diags x 1536 floats

typedef __attribute__((ext_vector_type(8))) short bf16x8;   // 8 bf16 = 4 VGPRs
typedef __attribute__((ext_vector_type(4))) float f32x4;
typedef unsigned short ushort_t;
typedef unsigned int uint_t;

// Diagonal layout for sim/V/E matrices (NW-dense): element (row z, col c):
//   addr = (z/6 + c/4)*1536 + (z%6)*256 + (z/6)*4 + (c&3)
__device__ __forceinline__ void stD(float* sp, int z, int c, float v) {
    int dl = z / 6, dr = z - dl * 6;
    sp[(size_t)(dl + (c >> 2)) * 1536 + dr * 256 + dl * 4 + (c & 3)] = v;
}

// RNE f32 -> bf16 bits
__device__ __forceinline__ ushort_t f2bf(float v) {
    uint_t u = __float_as_uint(v);
    uint_t r = (u + 0x7FFFu + ((u >> 16) & 1u)) >> 16;
    return (ushort_t)r;
}

// ---------------- weight split: conv_w (D, A*K) -> k-major wcol hi/lo [ks][d][32] ----------------
__global__ void wsplit_kernel(const float* __restrict__ w, ushort_t* __restrict__ wh,
                              ushort_t* __restrict__ wl) {
    int o = blockIdx.x * blockDim.x + threadIdx.x;   // o = d*KC + r
    if (o >= D_ * KC) return;
    int d = o / KC, r = o - d * KC;
    float v = (r < A_ * K_) ? w[(size_t)d * (A_ * K_) + r] : 0.0f;
    ushort_t h = f2bf(v);
    float hf = __uint_as_float(((uint_t)h) << 16);
    size_t oo = ((size_t)(r >> 5) * D_ + d) * 32 + (r & 31);
    wh[oo] = h;
    wl[oo] = f2bf(v - hf);
}

// ---------------- im2col: x (B,A,L) -> k-major xcol hi/lo [b][ks][l][32] ----------------
__global__ __launch_bounds__(256) void im2col_kernel(const float* __restrict__ x,
                                                     ushort_t* __restrict__ xh,
                                                     ushort_t* __restrict__ xl) {
    int b  = blockIdx.y;
    int lt = blockIdx.x;                 // 0..5, 64 l's each
    const float* xb = x + (size_t)b * A_ * L_;
    for (int idx = threadIdx.x; idx < 64 * KC; idx += 256) {
        int l = lt * 64 + idx / KC;
        int r = idx % KC;
        float v = 0.0f;
        if (r < A_ * K_) {
            int a = r / K_, kk = r - a * K_;
            int g = l + kk - 8;
            if (g >= 0 && g < L_) v = xb[(size_t)a * L_ + g];
        }
        ushort_t h = f2bf(v);
        float hf = __uint_as_float(((uint_t)h) << 16);
        size_t o = (((size_t)b * 15 + (r >> 5)) * L_ + l) * 32 + (r & 31);
        xh[o] = h;
        xl[o] = f2bf(v - hf);
    }
}

// ---------------- conv as split-bf16 MFMA GEMM (k-major streams, dense loads) ----------------
__global__ __launch_bounds__(256) void convmm_kernel(const ushort_t* __restrict__ xh,
                                                     const ushort_t* __restrict__ xl,
                                                     const ushort_t* __restrict__ wh,
                                                     const ushort_t* __restrict__ wl,
                                                     const float* __restrict__ bias,
                                                     ushort_t* __restrict__ ehi,
                                                     ushort_t* __restrict__ elo) {
    int b = blockIdx.z;
    int w = threadIdx.x >> 6;
    int lane = threadIdx.x & 63;
    int l0 = blockIdx.y * 64 + 32 * (w >> 1);
    int d0 = blockIdx.x * 64 + 32 * (w & 1);
    int r = lane & 15, g = lane >> 4;
    const ushort_t* pah = xh + (((size_t)b * 15) * L_ + l0 + r) * 32 + g * 8;
    const ushort_t* pal = xl + (((size_t)b * 15) * L_ + l0 + r) * 32 + g * 8;
    const ushort_t* pbh = wh + (size_t)(d0 + r) * 32 + g * 8;
    const ushort_t* pbl = wl + (size_t)(d0 + r) * 32 + g * 8;
    f32x4 acc00 = {0.f, 0.f, 0.f, 0.f}, acc01 = acc00, acc10 = acc00, acc11 = acc00;
#pragma unroll 3
    for (int ks = 0; ks < 15; ++ks) {
        size_t offA = (size_t)ks * L_ * 32;
        size_t offB = (size_t)ks * D_ * 32;
        bf16x8 Ah0 = *(const bf16x8*)(pah + offA);
        bf16x8 Ah1 = *(const bf16x8*)(pah + offA + 16 * 32);
        bf16x8 Al0 = *(const bf16x8*)(pal + offA);
        bf16x8 Al1 = *(const bf16x8*)(pal + offA + 16 * 32);
        bf16x8 Bh0 = *(const bf16x8*)(pbh + offB);
        bf16x8 Bh1 = *(const bf16x8*)(pbh + offB + 16 * 32);
        bf16x8 Bl0 = *(const bf16x8*)(pbl + offB);
        bf16x8 Bl1 = *(const bf16x8*)(pbl + offB + 16 * 32);
        acc00 = __builtin_amdgcn_mfma_f32_16x16x32_bf16(Ah0, Bh0, acc00, 0, 0, 0);
        acc00 = __builtin_amdgcn_mfma_f32_16x16x32_bf16(Ah0, Bl0, acc00, 0, 0, 0);
        acc00 = __builtin_amdgcn_mfma_f32_16x16x32_bf16(Al0, Bh0, acc00, 0, 0, 0);
        acc01 = __builtin_amdgcn_mfma_f32_16x16x32_bf16(Ah0, Bh1, acc01, 0, 0, 0);
        acc01 = __builtin_amdgcn_mfma_f32_16x16x32_bf16(Ah0, Bl1, acc01, 0, 0, 0);
        acc01 = __builtin_amdgcn_mfma_f32_16x16x32_bf16(Al0, Bh1, acc01, 0, 0, 0);
        acc10 = __builtin_amdgcn_mfma_f32_16x16x32_bf16(Ah1, Bh0, acc10, 0, 0, 0);
        acc10 = __builtin_amdgcn_mfma_f32_16x16x32_bf16(Ah1, Bl0, acc10, 0, 0, 0);
        acc10 = __builtin_amdgcn_mfma_f32_16x16x32_bf16(Al1, Bh0, acc10, 0, 0, 0);
        acc11 = __builtin_amdgcn_mfma_f32_16x16x32_bf16(Ah1, Bh1, acc11, 0, 0, 0);
        acc11 = __builtin_amdgcn_mfma_f32_16x16x32_bf16(Ah1, Bl1, acc11, 0, 0, 0);
        acc11 = __builtin_amdgcn_mfma_f32_16x16x32_bf16(Al1, Bh1, acc11, 0, 0, 0);
    }
#pragma unroll
    for (int v = 0; v < 4; ++v) {
        int lr0 = l0 + g * 4 + v, lr1 = lr0 + 16;
        int dc0 = d0 + r,         dc1 = dc0 + 16;
        float vals[4] = {acc00[v] + bias[dc0], acc01[v] + bias[dc1],
                         acc10[v] + bias[dc0], acc11[v] + bias[dc1]};
        int lrs[4] = {lr0, lr0, lr1, lr1};
        int dcs[4] = {dc0, dc1, dc0, dc1};
#pragma unroll
        for (int t = 0; t < 4; ++t) {
            ushort_t h = f2bf(vals[t]);
            float hf = __uint_as_float(((uint_t)h) << 16);
            size_t o = (((size_t)b * 16 + (dcs[t] >> 5)) * L_ + lrs[t]) * 32 + (dcs[t] & 31);
            ehi[o] = h;
            elo[o] = f2bf(vals[t] - hf);
        }
    }
}

// ---------------- sim = E_b · E_0^T via split-bf16 MFMA (k-major streams); writes diag layout ----------------
__global__ __launch_bounds__(256) void sim_kernel(const ushort_t* __restrict__ ehi,
                                                  const ushort_t* __restrict__ elo,
                                                  float* __restrict__ simD) {
    int b = blockIdx.z;
    int w = threadIdx.x >> 6;
    int lane = threadIdx.x & 63;
    int l0 = blockIdx.y * 64 + 32 * (w >> 1);
    int m0 = blockIdx.x * 64 + 32 * (w & 1);
    int r = lane & 15, g = lane >> 4;
    const ushort_t* pah = ehi + (((size_t)b * 16) * L_ + l0 + r) * 32 + g * 8;
    const ushort_t* pal = elo + (((size_t)b * 16) * L_ + l0 + r) * 32 + g * 8;
    const ushort_t* pbh = ehi + ((size_t)(m0 + r)) * 32 + g * 8;   // batch 0
    const ushort_t* pbl = elo + ((size_t)(m0 + r)) * 32 + g * 8;
    f32x4 acc00 = {0.f, 0.f, 0.f, 0.f}, acc01 = acc00, acc10 = acc00, acc11 = acc00;
#pragma unroll 2
    for (int ks = 0; ks < 16; ++ks) {
        size_t off = (size_t)ks * L_ * 32;
        bf16x8 Ah0 = *(const bf16x8*)(pah + off);
        bf16x8 Ah1 = *(const bf16x8*)(pah + off + 16 * 32);
        bf16x8 Al0 = *(const bf16x8*)(pal + off);
        bf16x8 Al1 = *(const bf16x8*)(pal + off + 16 * 32);
        bf16x8 Bh0 = *(const bf16x8*)(pbh + off);
        bf16x8 Bh1 = *(const bf16x8*)(pbh + off + 16 * 32);
        bf16x8 Bl0 = *(const bf16x8*)(pbl + off);
        bf16x8 Bl1 = *(const bf16x8*)(pbl + off + 16 * 32);
        acc00 = __builtin_amdgcn_mfma_f32_16x16x32_bf16(Ah0, Bh0, acc00, 0, 0, 0);
        acc00 = __builtin_amdgcn_mfma_f32_16x16x32_bf16(Ah0, Bl0, acc00, 0, 0, 0);
        acc00 = __builtin_amdgcn_mfma_f32_16x16x32_bf16(Al0, Bh0, acc00, 0, 0, 0);
        acc01 = __builtin_amdgcn_mfma_f32_16x16x32_bf16(Ah0, Bh1, acc01, 0, 0, 0);
        acc01 = __builtin_amdgcn_mfma_f32_16x16x32_bf16(Ah0, Bl1, acc01, 0, 0, 0);
        acc01 = __builtin_amdgcn_mfma_f32_16x16x32_bf16(Al0, Bh1, acc01, 0, 0, 0);
        acc10 = __builtin_amdgcn_mfma_f32_16x16x32_bf16(Ah1, Bh0, acc10, 0, 0, 0);
        acc10 = __builtin_amdgcn_mfma_f32_16x16x32_bf16(Ah1, Bl0, acc10, 0, 0, 0);
        acc10 = __builtin_amdgcn_mfma_f32_16x16x32_bf16(Al1, Bh0, acc10, 0, 0, 0);
        acc11 = __builtin_amdgcn_mfma_f32_16x16x32_bf16(Ah1, Bh1, acc11, 0, 0, 0);
        acc11 = __builtin_amdgcn_mfma_f32_16x16x32_bf16(Ah1, Bl1, acc11, 0, 0, 0);
        acc11 = __builtin_amdgcn_mfma_f32_16x16x32_bf16(Al1, Bh1, acc11, 0, 0, 0);
    }
    float* sp = simD + (size_t)b * SZD;
#pragma unroll
    for (int v = 0; v < 4; ++v) {
        int ar0 = l0 + g * 4 + v, ar1 = ar0 + 16;
        int ac0 = m0 + r,         ac1 = ac0 + 16;
        stD(sp, ar0, ac0, acc00[v]);
        stD(sp, ar0, ac1, acc01[v]);
        stD(sp, ar1, ac0, acc10[v]);
        stD(sp, ar1, ac1, acc11[v]);
    }
}

// ---------------- NW forward: 4-wave mailbox pipeline, mini-diagonal cell order ----------------
// V[i,j] = sim[i-1,j-1] + smoothmax3(V[i-1,j-1], V[i-1,j], V[i,j-1])   (g=0, t=1)
// 6x4 cell block has critical path 9 (diagonals d=r+q); explicit vout[][] + diagonal
// order exposes the ILP to the scheduler (identical FP ops per cell -> bit-identical).
__global__ __launch_bounds__(256, 1) void nw_fwd_kernel(const float* __restrict__ simD, float* __restrict__ VD) {
    int b = blockIdx.x;
    int tid = threadIdx.x;
    int w = tid >> 6, l = tid & 63;
    __shared__ float4 MA[4][64], MB4[4][64], MC[4][64];
    __shared__ int FL[4];
    const float4 Z4 = {0.f, 0.f, 0.f, 0.f};
    {
        int s = tid >> 6, ll = tid & 63;
        MA[s][ll] = Z4; MB4[s][ll] = Z4; MC[s][ll] = Z4;
    }
    if (tid < 4) FL[tid] = (tid == 3) ? -1 : -1000000;
    __syncthreads();
    volatile int* flg = FL;
    const float* pS = simD + (size_t)b * SZD + l * 4;
    float*       pV = VD   + (size_t)b * SZD + l * 4;
    float4 buf[6];
#pragma unroll
    for (int r = 0; r < 6; ++r) buf[r] = *(const float4*)(pS + w * 1536 + r * 256);
    int lm = (l == 0) ? 0 : (l - 1);
#pragma unroll 1
    for (int T = w; T < 159; T += 4) {
        int sp = (T - 1) & 3;
        while (flg[sp] != T - 1) {}
        asm volatile("" ::: "memory");
        float4 Ar = MA[sp][l];
        float4 Bs = MB4[sp][l];
        float4 Cs = MC[sp][l];
        float4 Bn = MB4[sp][lm];
        float4 Cn = MC[sp][lm];
        if (l == 0) { Bn = Z4; Cn = Z4; }
        float vleft[6] = {Ar.x, Ar.y, Ar.z, Ar.w, Bs.x, Bs.y};
        float d0 = Bn.z;                              // V[6l, c0]
        float uin[4] = {Cn.x, Cn.y, Cn.z, Cn.w};      // V[6l, c0+q+1]
        float sc[6][4];
#pragma unroll
        for (int r = 0; r < 6; ++r) {
            sc[r][0] = buf[r].x; sc[r][1] = buf[r].y; sc[r][2] = buf[r].z; sc[r][3] = buf[r].w;
        }
        int dP = min(T + 4, 158);
#pragma unroll
        for (int r = 0; r < 6; ++r) buf[r] = *(const float4*)(pS + dP * 1536 + r * 256);
        int ct = T - l;
        float nbc[4] = {0.f, 0.f, 0.f, 0.f}, nbp = 0.f;
        if (ct >= 0 && ct <= 95) {
            float vout[6][4];
#pragma unroll
            for (int dd = 0; dd < 9; ++dd) {
#pragma unroll
                for (int r = 0; r < 6; ++r) {
                    const int q = dd - r;
                    if (q < 0 || q > 3) continue;
                    float dg = (r == 0) ? ((q == 0) ? d0 : uin[q - 1])
                                        : ((q == 0) ? vleft[r - 1] : vout[r - 1][q - 1]);
                    float up = (r == 0) ? uin[q] : vout[r - 1][q];
                    float lf = (q == 0) ? vleft[r] : vout[r][q - 1];
                    float mx = fmaxf(dg, fmaxf(up, lf));
                    vout[r][q] = sc[r][q] + mx +
                        __logf(__expf(dg - mx) + __expf(up - mx) + __expf(lf - mx));
                }
            }
            nbp = Cs.w;                               // own old bcarry[3] = V[6l+6, 4ct]
#pragma unroll
            for (int q = 0; q < 4; ++q) nbc[q] = vout[5][q];
#pragma unroll
            for (int r = 0; r < 6; ++r) vleft[r] = vout[r][3];
            float* pVd = pV + (size_t)T * 1536;
#pragma unroll
            for (int r = 0; r < 6; ++r) {
                float4 t;
                t.x = vout[r][0]; t.y = vout[r][1]; t.z = vout[r][2]; t.w = vout[r][3];
                *(float4*)(pVd + r * 256) = t;
            }
        }
        float4 pa; pa.x = vleft[0]; pa.y = vleft[1]; pa.z = vleft[2]; pa.w = vleft[3];
        float4 pb; pb.x = vleft[4]; pb.y = vleft[5]; pb.z = nbp; pb.w = 0.f;
        float4 pc; pc.x = nbc[0]; pc.y = nbc[1]; pc.z = nbc[2]; pc.w = nbc[3];
        MA[w][l] = pa; MB4[w][l] = pb; MC[w][l] = pc;
        asm volatile("s_waitcnt lgkmcnt(0)" ::: "memory");
        if (l == 0) flg[w] = T;
    }
}

// ---------------- NW backward: 4-wave mailbox pipeline, hoisted exps + diagonal E-chain ----------------
// All U values and exp-weights are independent of the E recurrence -> computed first;
// the E-chain is then a pure 3-FMA/cell mini-DP with critical path 9.
__global__ __launch_bounds__(256, 1) void nw_bwd_kernel(const float* __restrict__ simD,
                                                        const float* __restrict__ VD,
                                                        const int* __restrict__ shapes,
                                                        float* __restrict__ ED) {
    int b = blockIdx.x;
    int tid = threadIdx.x;
    int w = tid >> 6, l = tid & 63;
    __shared__ float4 MA[4][64], MB4[4][64], MC[4][64], MD[4][64], MEx[4][64], MF[4][64];
    __shared__ int FL[4];
    const float4 Z4 = {0.f, 0.f, 0.f, 0.f};
    {
        int s = tid >> 6, ll = tid & 63;
        MA[s][ll] = Z4; MB4[s][ll] = Z4; MC[s][ll] = Z4;
        MD[s][ll] = Z4; MEx[s][ll] = Z4; MF[s][ll] = Z4;
    }
    if (tid < 4) FL[tid] = (tid == 3) ? -1 : -1000000;
    __syncthreads();
    volatile int* flg = FL;
    const float* pS = simD + (size_t)b * SZD + l * 4;
    const float* pV = VD   + (size_t)b * SZD + l * 4;
    float*       pE = ED   + (size_t)b * SZD + l * 4;
    int li = min(max(shapes[2 * b + 0], 0), L_);
    int lj = min(max(shapes[2 * b + 1], 0), L_);
    float4 bufV[6], bufS[6];
#pragma unroll
    for (int r = 0; r < 6; ++r) {
        bufV[r] = *(const float4*)(pV + (158 - w) * 1536 + r * 256);
        bufS[r] = *(const float4*)(pS + (158 - w) * 1536 + r * 256);
    }
    int lp = (l == 63) ? 63 : (l + 1);
#pragma unroll 1
    for (int T = w; T < 159; T += 4) {
        int sp = (T - 1) & 3;
        while (flg[sp] != T - 1) {}
        asm volatile("" ::: "memory");
        float4 Ar = MA[sp][l];
        float4 Br = MB4[sp][l];
        float4 Cr = MC[sp][l];
        float4 Dn = MD[sp][lp];
        float4 En = MEx[sp][lp];
        float4 Fn = MF[sp][lp];
        if (l == 63) { Dn = Z4; En = Z4; Fn = Z4; }
        float einit[6] = {Ar.x, Ar.y, Ar.z, Ar.w, Br.x, Br.y};
        float uinit[6] = {Br.z, Br.w, Cr.x, Cr.y, Cr.z, Cr.w};
        float enb_c[4] = {Dn.x, Dn.y, Dn.z, Dn.w};   // E[6l+7, c0+1+q]
        float unb_c[4] = {En.x, En.y, En.z, En.w};   // U[6l+7, c0+1+q]
        float enbtd_s = Fn.x, unbtd_s = Fn.y;        // E/U[6l+7, rightmost+1]
        float Vq[6][4], Sq[6][4];
#pragma unroll
        for (int r = 0; r < 6; ++r) {
            Vq[r][0] = bufV[r].x; Vq[r][1] = bufV[r].y; Vq[r][2] = bufV[r].z; Vq[r][3] = bufV[r].w;
            Sq[r][0] = bufS[r].x; Sq[r][1] = bufS[r].y; Sq[r][2] = bufS[r].z; Sq[r][3] = bufS[r].w;
        }
        int dP = max(158 - (T + 4), 0);
#pragma unroll
        for (int r = 0; r < 6; ++r) {
            bufV[r] = *(const float4*)(pV + dP * 1536 + r * 256);
            bufS[r] = *(const float4*)(pS + dP * 1536 + r * 256);
        }
        int ct = 158 - T - l;
        float necar[4] = {0.f, 0.f, 0.f, 0.f}, nucar[4] = {0.f, 0.f, 0.f, 0.f};
        float eC[6], uC[6];
#pragma unroll
        for (int r = 0; r < 6; ++r) { eC[r] = einit[r]; uC[r] = uinit[r]; }
        if (ct >= 0 && ct <= 95) {
            // ---- phase 1: all U values (independent) ----
            float Uo[6][4];
#pragma unroll
            for (int r = 0; r < 6; ++r)
#pragma unroll
                for (int q = 0; q < 4; ++q)
                    Uo[r][q] = Vq[r][q] - Sq[r][q];
            // ---- phase 2: all 72 exp-weights (independent of E-chain) ----
            float wtd[6][4], wtu[6][4], wtl[6][4];
#pragma unroll
            for (int r = 0; r < 6; ++r) {
                int i = 6 * l + r + 1;
                bool ilt = (i < L_);
#pragma unroll
                for (int q = 0; q < 4; ++q) {
                    int j = 4 * ct + q + 1;
                    bool jlt = (j < L_);
                    float ub_old = (r == 5) ? ((q == 3) ? unbtd_s : unb_c[q + 1])
                                            : ((q == 3) ? uinit[r + 1] : Uo[r + 1][q + 1]);
                    float ub_new = (r == 5) ? unb_c[q] : Uo[r + 1][q];
                    float uo_r   = (q == 3) ? uinit[r] : Uo[r][q + 1];
                    wtd[r][q] = (ilt && jlt) ? __expf(Vq[r][q] - ub_old) : 0.f;
                    wtu[r][q] = ilt ? __expf(Vq[r][q] - ub_new) : 0.f;
                    wtl[r][q] = jlt ? __expf(Vq[r][q] - uo_r) : 0.f;
                }
            }
            // ---- phase 3: E recurrence, mini-diagonal order (3 FMA/cell, path 9) ----
            float Eo[6][4];
#pragma unroll
            for (int dd = 0; dd < 9; ++dd) {
#pragma unroll
                for (int r = 5; r >= 0; --r) {
                    const int q = 8 - dd - r;
                    if (q < 0 || q > 3) continue;
                    int i = 6 * l + r + 1;
                    int j = 4 * ct + q + 1;
                    float eb_old = (r == 5) ? ((q == 3) ? enbtd_s : enb_c[q + 1])
                                            : ((q == 3) ? einit[r + 1] : Eo[r + 1][q + 1]);
                    float eb_new = (r == 5) ? enb_c[q] : Eo[r + 1][q];
                    float eo_r   = (q == 3) ? einit[r] : Eo[r][q + 1];
                    float en = (i == li && j == lj) ? 1.f : 0.f;
                    en += wtd[r][q] * eb_old + wtu[r][q] * eb_new + wtl[r][q] * eo_r;
                    Eo[r][q] = en;
                }
            }
#pragma unroll
            for (int r = 0; r < 6; ++r) { eC[r] = Eo[r][0]; uC[r] = Uo[r][0]; }
#pragma unroll
            for (int q = 0; q < 4; ++q) { necar[q] = Eo[0][q]; nucar[q] = Uo[0][q]; }
            float* pEd = pE + (size_t)(158 - T) * 1536;
#pragma unroll
            for (int r = 0; r < 6; ++r) {
                float4 t;
                t.x = Eo[r][0]; t.y = Eo[r][1]; t.z = Eo[r][2]; t.w = Eo[r][3];
                *(float4*)(pEd + r * 256) = t;
            }
        }
        float4 pa; pa.x = eC[0]; pa.y = eC[1]; pa.z = eC[2]; pa.w = eC[3];
        float4 pb; pb.x = eC[4]; pb.y = eC[5]; pb.z = uC[0]; pb.w = uC[1];
        float4 pc; pc.x = uC[2]; pc.y = uC[3]; pc.z = uC[4]; pc.w = uC[5];
        float4 pd; pd.x = necar[0]; pd.y = necar[1]; pd.z = necar[2]; pd.w = necar[3];
        float4 pe; pe.x = nucar[0]; pe.y = nucar[1]; pe.z = nucar[2]; pe.w = nucar[3];
        float4 pf; pf.x = einit[0]; pf.y = uinit[0]; pf.z = 0.f; pf.w = 0.f;
        MA[w][l] = pa; MB4[w][l] = pb; MC[w][l] = pc;
        MD[w][l] = pd; MEx[w][l] = pe; MF[w][l] = pf;
        asm volatile("s_waitcnt lgkmcnt(0)" ::: "memory");
        if (l == 0) flg[w] = T;
    }
}

// ---------------- repack: EDiag (diag layout) -> Enat (B, L, L) row-major ----------------
__global__ __launch_bounds__(256) void repack_kernel(const float* __restrict__ ED,
                                                     float* __restrict__ Enat) {
    int n  = blockIdx.y;
    int jt = blockIdx.x;                 // 0..5
    int jl = threadIdx.x & 63;
    int gp = threadIdx.x >> 6;           // 0..3: i in [gp*96, gp*96+96)
    int j  = jt * 64 + jl;
    const float* eb = ED + (size_t)n * SZD + (j >> 2) * 1536 + (j & 3);
    float* ob = Enat + (size_t)n * LL + j;
#pragma unroll 4
    for (int i = gp * 96; i < gp * 96 + 96; ++i) {
        int dl = i / 6, dr = i - dl * 6;
        float v = eb[(size_t)dl * 1540 + dr * 256];   // dl*1536 + dl*4
        ob[(size_t)i * L_] = v;
    }
}

// ---------------- consensus[j,a] = (1/B) sum_n sum_i matrices[n,a,i]*E[n,i,j] ----------------
__global__ __launch_bounds__(256) void consensus_kernel(const float* __restrict__ x,      // (B,A,L)
                                                        const float* __restrict__ Enat,   // (B,L,L)
                                                        float* __restrict__ cons) {       // (L,A)
    int n  = blockIdx.y;
    int j0 = blockIdx.x * 64;
    __shared__ float ms[A_][L_];    // 39.9 KB: matrices[n] staged
    for (int idx = threadIdx.x; idx < A_ * L_; idx += 256)
        ((float*)ms)[idx] = x[(size_t)n * A_ * L_ + idx];
    __syncthreads();
    int jl = threadIdx.x & 63;
    int g  = threadIdx.x >> 6;      // 0..3
    int a0 = g * 7;                 // 0,7,14,21
    int na = (a0 + 7 <= A_) ? 7 : (A_ - a0);   // 7,7,7,5
    int j  = j0 + jl;
    float acc[7] = {0.f, 0.f, 0.f, 0.f, 0.f, 0.f, 0.f};
    const float* aE = Enat + (size_t)n * LL + j;
    for (int i = 0; i < L_; ++i) {
        float al = aE[(size_t)i * L_];
#pragma unroll
        for (int t = 0; t < 7; ++t)
            if (t < na) acc[t] = fmaf(al, ms[a0 + t][i], acc[t]);
    }
    for (int t = 0; t < na; ++t)
        atomicAdd(&cons[(size_t)j * A_ + a0 + t], acc[t] * (1.0f / B_));
}

// ---------------- out[n,i,a] = sum_j cons[j,a] * E[n,i,j] ----------------
__global__ __launch_bounds__(256) void out_kernel(const float* __restrict__ Enat,
                                                  const float* __restrict__ cons,
                                                  float* __restrict__ out) {
    int n  = blockIdx.y;
    int i0 = blockIdx.x * 32;
    __shared__ float cs[L_][A_];        // 40.0 KB
    __shared__ float as_[32][L_ + 1];   // 49.3 KB (pad: break 384-stride bank alias)
    for (int idx = threadIdx.x; idx < L_ * A_; idx += 256)
        ((float*)cs)[idx] = cons[idx];
    const float* aE = Enat + (size_t)n * LL;
    for (int idx = threadIdx.x; idx < 32 * L_; idx += 256) {
        int r = idx / L_, c = idx - r * L_;
        as_[r][c] = aE[(size_t)(i0 + r) * L_ + c];
    }
    __syncthreads();
    for (int o = threadIdx.x; o < 32 * A_; o += 256) {
        int il = o / A_, a = o % A_;
        float s = 0.f;
        for (int jj = 0; jj < L_; ++jj)
            s = fmaf(as_[il][jj], cs[jj][a], s);
        out[((size_t)n * L_ + i0 + il) * A_ + a] = s;
    }
}

extern "C" void kernel_launch(void* const* d_in, const int* in_sizes, int n_in,
                              void* d_out, int out_size, void* d_ws, size_t ws_size,
                              hipStream_t stream) {
    const float* matrices = (const float*)d_in[0];   // (B,A,L) f32
    const int*   shapes   = (const int*)d_in[1];     // (B,2) i32
    const float* conv_w   = (const float*)d_in[2];   // (D,A,K) f32
    const float* conv_b   = (const float*)d_in[3];   // (D,) f32
    float* out = (float*)d_out;                      // (B,L,A) f32

    char* p = (char*)d_ws;
    // region1 (62.9 MB): xcol hi/lo (47.2 MB) during conv; EDiag after bwd (xcol dead).
    float*    EDiag = (float*)p;
    ushort_t* xh = (ushort_t*)p;
    ushort_t* xl = xh + (size_t)B_ * 15 * L_ * 32;
    p += (size_t)B_ * SZD * 4;
    // region2 (50.3 MB): ehi/elo (dead after sim_kernel).
    ushort_t* ehi = (ushort_t*)p;
    ushort_t* elo = ehi + (size_t)B_ * 16 * L_ * 32;
    p += (size_t)B_ * L_ * D_ * 4;
    // region3 (62.9 MB): simD (dead after bwd) -> Enat (37.7 MB) for repack.
    float* simD = (float*)p;
    float* Enat = simD;
    p += (size_t)B_ * SZD * 4;
    // region4 (62.9 MB): VD.
    float* VD = (float*)p;
    p += (size_t)B_ * SZD * 4;
    ushort_t* wh = (ushort_t*)p;                     // 0.49 MB
    ushort_t* wl = wh + (size_t)15 * D_ * 32;        // 0.49 MB
    p += (size_t)15 * D_ * 32 * 4;
    float* cons = (float*)p;                         // 40 KB

    wsplit_kernel<<<(D_ * KC + 255) / 256, 256, 0, stream>>>(conv_w, wh, wl);
    im2col_kernel<<<dim3(L_ / 64, B_), 256, 0, stream>>>(matrices, xh, xl);
    convmm_kernel<<<dim3(D_ / 64, L_ / 64, B_), 256, 0, stream>>>(xh, xl, wh, wl, conv_b, ehi, elo);
    sim_kernel<<<dim3(L_ / 64, L_ / 64, B_), 256, 0, stream>>>(ehi, elo, simD);
    nw_fwd_kernel<<<B_, 256, 0, stream>>>(simD, VD);
    nw_bwd_kernel<<<B_, 256, 0, stream>>>(simD, VD, shapes, EDiag);
    repack_kernel<<<dim3(L_ / 64, B_), 256, 0, stream>>>(EDiag, Enat);
    hipMemsetAsync(cons, 0, (size_t)L_ * A_ * sizeof(float), stream);
    consensus_kernel<<<dim3(L_ / 64, B_), 256, 0, stream>>>(matrices, Enat, cons);
    out_kernel<<<dim3(L_ / 32, B_), 256, 0, stream>>>(Enat, cons, out);
}

// Round 16
// 930.880 us; speedup vs baseline: 1.0926x; 1.0118x over previous
//
#include <hip/hip_runtime.h>
#include <hip/hip_bf16.h>
#include <math.h>

#define B_  64
#define A_  26
#define L_  384
#define D_  512
#define K_  18
#define KC  480      // im2col K padded (468 -> 480, 15 slices of 32)
#define LL  147456   // L_*L_
#define SZD 245760   // per-batch diagonal-layout stride: 160 diags x 1536 floats

typedef __attribute__((ext_vector_type(8))) short bf16x8;   // 8 bf16 = 4 VGPRs
typedef __attribute__((ext_vector_type(4))) float f32x4;
typedef unsigned short ushort_t;
typedef unsigned int uint_t;

// Diagonal layout for sim/V/E matrices (NW-dense): element (row z, col c):
//   addr = (z/6 + c/4)*1536 + (z%6)*256 + (z/6)*4 + (c&3)
__device__ __forceinline__ void stD(float* sp, int z, int c, float v) {
    int dl = z / 6, dr = z - dl * 6;
    sp[(size_t)(dl + (c >> 2)) * 1536 + dr * 256 + dl * 4 + (c & 3)] = v;
}

// RNE f32 -> bf16 bits
__device__ __forceinline__ ushort_t f2bf(float v) {
    uint_t u = __float_as_uint(v);
    uint_t r = (u + 0x7FFFu + ((u >> 16) & 1u)) >> 16;
    return (ushort_t)r;
}

// ---------------- weight split: conv_w (D, A*K) -> k-major wcol hi/lo [ks][d][32] ----------------
__global__ void wsplit_kernel(const float* __restrict__ w, ushort_t* __restrict__ wh,
                              ushort_t* __restrict__ wl) {
    int o = blockIdx.x * blockDim.x + threadIdx.x;   // o = d*KC + r
    if (o >= D_ * KC) return;
    int d = o / KC, r = o - d * KC;
    float v = (r < A_ * K_) ? w[(size_t)d * (A_ * K_) + r] : 0.0f;
    ushort_t h = f2bf(v);
    float hf = __uint_as_float(((uint_t)h) << 16);
    size_t oo = ((size_t)(r >> 5) * D_ + d) * 32 + (r & 31);
    wh[oo] = h;
    wl[oo] = f2bf(v - hf);
}

// ---------------- im2col: x (B,A,L) -> k-major xcol hi/lo [b][ks][l][32] ----------------
__global__ __launch_bounds__(256) void im2col_kernel(const float* __restrict__ x,
                                                     ushort_t* __restrict__ xh,
                                                     ushort_t* __restrict__ xl) {
    int b  = blockIdx.y;
    int lt = blockIdx.x;                 // 0..5, 64 l's each
    const float* xb = x + (size_t)b * A_ * L_;
    for (int idx = threadIdx.x; idx < 64 * KC; idx += 256) {
        int l = lt * 64 + idx / KC;
        int r = idx % KC;
        float v = 0.0f;
        if (r < A_ * K_) {
            int a = r / K_, kk = r - a * K_;
            int g = l + kk - 8;
            if (g >= 0 && g < L_) v = xb[(size_t)a * L_ + g];
        }
        ushort_t h = f2bf(v);
        float hf = __uint_as_float(((uint_t)h) << 16);
        size_t o = (((size_t)b * 15 + (r >> 5)) * L_ + l) * 32 + (r & 31);
        xh[o] = h;
        xl[o] = f2bf(v - hf);
    }
}

// ---------------- conv as split-bf16 MFMA GEMM (k-major streams, dense loads) ----------------
__global__ __launch_bounds__(256) void convmm_kernel(const ushort_t* __restrict__ xh,
                                                     const ushort_t* __restrict__ xl,
                                                     const ushort_t* __restrict__ wh,
                                                     const ushort_t* __restrict__ wl,
                                                     const float* __restrict__ bias,
                                                     ushort_t* __restrict__ ehi,
                                                     ushort_t* __restrict__ elo) {
    int b = blockIdx.z;
    int w = threadIdx.x >> 6;
    int lane = threadIdx.x & 63;
    int l0 = blockIdx.y * 64 + 32 * (w >> 1);
    int d0 = blockIdx.x * 64 + 32 * (w & 1);
    int r = lane & 15, g = lane >> 4;
    const ushort_t* pah = xh + (((size_t)b * 15) * L_ + l0 + r) * 32 + g * 8;
    const ushort_t* pal = xl + (((size_t)b * 15) * L_ + l0 + r) * 32 + g * 8;
    const ushort_t* pbh = wh + (size_t)(d0 + r) * 32 + g * 8;
    const ushort_t* pbl = wl + (size_t)(d0 + r) * 32 + g * 8;
    f32x4 acc00 = {0.f, 0.f, 0.f, 0.f}, acc01 = acc00, acc10 = acc00, acc11 = acc00;
#pragma unroll 3
    for (int ks = 0; ks < 15; ++ks) {
        size_t offA = (size_t)ks * L_ * 32;
        size_t offB = (size_t)ks * D_ * 32;
        bf16x8 Ah0 = *(const bf16x8*)(pah + offA);
        bf16x8 Ah1 = *(const bf16x8*)(pah + offA + 16 * 32);
        bf16x8 Al0 = *(const bf16x8*)(pal + offA);
        bf16x8 Al1 = *(const bf16x8*)(pal + offA + 16 * 32);
        bf16x8 Bh0 = *(const bf16x8*)(pbh + offB);
        bf16x8 Bh1 = *(const bf16x8*)(pbh + offB + 16 * 32);
        bf16x8 Bl0 = *(const bf16x8*)(pbl + offB);
        bf16x8 Bl1 = *(const bf16x8*)(pbl + offB + 16 * 32);
        acc00 = __builtin_amdgcn_mfma_f32_16x16x32_bf16(Ah0, Bh0, acc00, 0, 0, 0);
        acc00 = __builtin_amdgcn_mfma_f32_16x16x32_bf16(Ah0, Bl0, acc00, 0, 0, 0);
        acc00 = __builtin_amdgcn_mfma_f32_16x16x32_bf16(Al0, Bh0, acc00, 0, 0, 0);
        acc01 = __builtin_amdgcn_mfma_f32_16x16x32_bf16(Ah0, Bh1, acc01, 0, 0, 0);
        acc01 = __builtin_amdgcn_mfma_f32_16x16x32_bf16(Ah0, Bl1, acc01, 0, 0, 0);
        acc01 = __builtin_amdgcn_mfma_f32_16x16x32_bf16(Al0, Bh1, acc01, 0, 0, 0);
        acc10 = __builtin_amdgcn_mfma_f32_16x16x32_bf16(Ah1, Bh0, acc10, 0, 0, 0);
        acc10 = __builtin_amdgcn_mfma_f32_16x16x32_bf16(Ah1, Bl0, acc10, 0, 0, 0);
        acc10 = __builtin_amdgcn_mfma_f32_16x16x32_bf16(Al1, Bh0, acc10, 0, 0, 0);
        acc11 = __builtin_amdgcn_mfma_f32_16x16x32_bf16(Ah1, Bh1, acc11, 0, 0, 0);
        acc11 = __builtin_amdgcn_mfma_f32_16x16x32_bf16(Ah1, Bl1, acc11, 0, 0, 0);
        acc11 = __builtin_amdgcn_mfma_f32_16x16x32_bf16(Al1, Bh1, acc11, 0, 0, 0);
    }
#pragma unroll
    for (int v = 0; v < 4; ++v) {
        int lr0 = l0 + g * 4 + v, lr1 = lr0 + 16;
        int dc0 = d0 + r,         dc1 = dc0 + 16;
        float vals[4] = {acc00[v] + bias[dc0], acc01[v] + bias[dc1],
                         acc10[v] + bias[dc0], acc11[v] + bias[dc1]};
        int lrs[4] = {lr0, lr0, lr1, lr1};
        int dcs[4] = {dc0, dc1, dc0, dc1};
#pragma unroll
        for (int t = 0; t < 4; ++t) {
            ushort_t h = f2bf(vals[t]);
            float hf = __uint_as_float(((uint_t)h) << 16);
            size_t o = (((size_t)b * 16 + (dcs[t] >> 5)) * L_ + lrs[t]) * 32 + (dcs[t] & 31);
            ehi[o] = h;
            elo[o] = f2bf(vals[t] - hf);
        }
    }
}

// ---------------- sim = E_b · E_0^T via split-bf16 MFMA (k-major streams); writes diag layout ----------------
__global__ __launch_bounds__(256) void sim_kernel(const ushort_t* __restrict__ ehi,
                                                  const ushort_t* __restrict__ elo,
                                                  float* __restrict__ simD) {
    int b = blockIdx.z;
    int w = threadIdx.x >> 6;
    int lane = threadIdx.x & 63;
    int l0 = blockIdx.y * 64 + 32 * (w >> 1);
    int m0 = blockIdx.x * 64 + 32 * (w & 1);
    int r = lane & 15, g = lane >> 4;
    const ushort_t* pah = ehi + (((size_t)b * 16) * L_ + l0 + r) * 32 + g * 8;
    const ushort_t* pal = elo + (((size_t)b * 16) * L_ + l0 + r) * 32 + g * 8;
    const ushort_t* pbh = ehi + ((size_t)(m0 + r)) * 32 + g * 8;   // batch 0
    const ushort_t* pbl = elo + ((size_t)(m0 + r)) * 32 + g * 8;
    f32x4 acc00 = {0.f, 0.f, 0.f, 0.f}, acc01 = acc00, acc10 = acc00, acc11 = acc00;
#pragma unroll 2
    for (int ks = 0; ks < 16; ++ks) {
        size_t off = (size_t)ks * L_ * 32;
        bf16x8 Ah0 = *(const bf16x8*)(pah + off);
        bf16x8 Ah1 = *(const bf16x8*)(pah + off + 16 * 32);
        bf16x8 Al0 = *(const bf16x8*)(pal + off);
        bf16x8 Al1 = *(const bf16x8*)(pal + off + 16 * 32);
        bf16x8 Bh0 = *(const bf16x8*)(pbh + off);
        bf16x8 Bh1 = *(const bf16x8*)(pbh + off + 16 * 32);
        bf16x8 Bl0 = *(const bf16x8*)(pbl + off);
        bf16x8 Bl1 = *(const bf16x8*)(pbl + off + 16 * 32);
        acc00 = __builtin_amdgcn_mfma_f32_16x16x32_bf16(Ah0, Bh0, acc00, 0, 0, 0);
        acc00 = __builtin_amdgcn_mfma_f32_16x16x32_bf16(Ah0, Bl0, acc00, 0, 0, 0);
        acc00 = __builtin_amdgcn_mfma_f32_16x16x32_bf16(Al0, Bh0, acc00, 0, 0, 0);
        acc01 = __builtin_amdgcn_mfma_f32_16x16x32_bf16(Ah0, Bh1, acc01, 0, 0, 0);
        acc01 = __builtin_amdgcn_mfma_f32_16x16x32_bf16(Ah0, Bl1, acc01, 0, 0, 0);
        acc01 = __builtin_amdgcn_mfma_f32_16x16x32_bf16(Al0, Bh1, acc01, 0, 0, 0);
        acc10 = __builtin_amdgcn_mfma_f32_16x16x32_bf16(Ah1, Bh0, acc10, 0, 0, 0);
        acc10 = __builtin_amdgcn_mfma_f32_16x16x32_bf16(Ah1, Bl0, acc10, 0, 0, 0);
        acc10 = __builtin_amdgcn_mfma_f32_16x16x32_bf16(Al1, Bh0, acc10, 0, 0, 0);
        acc11 = __builtin_amdgcn_mfma_f32_16x16x32_bf16(Ah1, Bh1, acc11, 0, 0, 0);
        acc11 = __builtin_amdgcn_mfma_f32_16x16x32_bf16(Ah1, Bl1, acc11, 0, 0, 0);
        acc11 = __builtin_amdgcn_mfma_f32_16x16x32_bf16(Al1, Bh1, acc11, 0, 0, 0);
    }
    float* sp = simD + (size_t)b * SZD;
#pragma unroll
    for (int v = 0; v < 4; ++v) {
        int ar0 = l0 + g * 4 + v, ar1 = ar0 + 16;
        int ac0 = m0 + r,         ac1 = ac0 + 16;
        stD(sp, ar0, ac0, acc00[v]);
        stD(sp, ar0, ac1, acc01[v]);
        stD(sp, ar1, ac0, acc10[v]);
        stD(sp, ar1, ac1, acc11[v]);
    }
}

// ---------------- NW forward: 4-wave mailbox pipeline; publish path touches ONLY LDS ----------------
// V[i,j] = sim[i-1,j-1] + smoothmax3(V[i-1,j-1], V[i-1,j], V[i,j-1])   (g=0, t=1)
// Global V-stores and sim-prefetch are issued AFTER the flag publish: flat_* ops count
// in lgkmcnt (ISA §7), so any global op in flight would stall the publish s_waitcnt.
__global__ __launch_bounds__(256, 1) void nw_fwd_kernel(const float* __restrict__ simD, float* __restrict__ VD) {
    int b = blockIdx.x;
    int tid = threadIdx.x;
    int w = tid >> 6, l = tid & 63;
    __shared__ float4 MA[4][64], MB4[4][64], MC[4][64];
    __shared__ int FL[4];
    const float4 Z4 = {0.f, 0.f, 0.f, 0.f};
    {
        int s = tid >> 6, ll = tid & 63;
        MA[s][ll] = Z4; MB4[s][ll] = Z4; MC[s][ll] = Z4;
    }
    if (tid < 4) FL[tid] = (tid == 3) ? -1 : -1000000;
    __syncthreads();
    volatile int* flg = FL;
    const float* pS = simD + (size_t)b * SZD + l * 4;
    float*       pV = VD   + (size_t)b * SZD + l * 4;
    float4 buf[6];
#pragma unroll
    for (int r = 0; r < 6; ++r) buf[r] = *(const float4*)(pS + w * 1536 + r * 256);
    int lm = (l == 0) ? 0 : (l - 1);
#pragma unroll 1
    for (int T = w; T < 159; T += 4) {
        int sp = (T - 1) & 3;
        while (flg[sp] != T - 1) {}
        asm volatile("" ::: "memory");
        float4 Ar = MA[sp][l];
        float4 Bs = MB4[sp][l];
        float4 Cs = MC[sp][l];
        float4 Bn = MB4[sp][lm];
        float4 Cn = MC[sp][lm];
        if (l == 0) { Bn = Z4; Cn = Z4; }
        float vleft[6] = {Ar.x, Ar.y, Ar.z, Ar.w, Bs.x, Bs.y};
        float d0 = Bn.z;                              // V[6l, c0]
        float uin[4] = {Cn.x, Cn.y, Cn.z, Cn.w};      // V[6l, c0+q+1]
        float sc[6][4];
#pragma unroll
        for (int r = 0; r < 6; ++r) {
            sc[r][0] = buf[r].x; sc[r][1] = buf[r].y; sc[r][2] = buf[r].z; sc[r][3] = buf[r].w;
        }
        int ct = T - l;
        bool act = (ct >= 0 && ct <= 95);
        float nbc[4] = {0.f, 0.f, 0.f, 0.f}, nbp = 0.f;
        float vout[6][4];
        if (act) {
#pragma unroll
            for (int dd = 0; dd < 9; ++dd) {
#pragma unroll
                for (int r = 0; r < 6; ++r) {
                    const int q = dd - r;
                    if (q < 0 || q > 3) continue;
                    float dg = (r == 0) ? ((q == 0) ? d0 : uin[q - 1])
                                        : ((q == 0) ? vleft[r - 1] : vout[r - 1][q - 1]);
                    float up = (r == 0) ? uin[q] : vout[r - 1][q];
                    float lf = (q == 0) ? vleft[r] : vout[r][q - 1];
                    float mx = fmaxf(dg, fmaxf(up, lf));
                    vout[r][q] = sc[r][q] + mx +
                        __logf(__expf(dg - mx) + __expf(up - mx) + __expf(lf - mx));
                }
            }
            nbp = Cs.w;                               // own old bcarry[3] = V[6l+6, 4ct]
#pragma unroll
            for (int q = 0; q < 4; ++q) nbc[q] = vout[5][q];
#pragma unroll
            for (int r = 0; r < 6; ++r) vleft[r] = vout[r][3];
        }
        // ---- publish (LDS only) ----
        float4 pa; pa.x = vleft[0]; pa.y = vleft[1]; pa.z = vleft[2]; pa.w = vleft[3];
        float4 pb; pb.x = vleft[4]; pb.y = vleft[5]; pb.z = nbp; pb.w = 0.f;
        float4 pc; pc.x = nbc[0]; pc.y = nbc[1]; pc.z = nbc[2]; pc.w = nbc[3];
        MA[w][l] = pa; MB4[w][l] = pb; MC[w][l] = pc;
        asm volatile("s_waitcnt lgkmcnt(0)" ::: "memory");
        if (l == 0) flg[w] = T;
        asm volatile("" ::: "memory");
        // ---- global ops AFTER publish ----
        if (act) {
            float* pVd = pV + (size_t)T * 1536;
#pragma unroll
            for (int r = 0; r < 6; ++r) {
                float4 t;
                t.x = vout[r][0]; t.y = vout[r][1]; t.z = vout[r][2]; t.w = vout[r][3];
                *(float4*)(pVd + r * 256) = t;
            }
        }
        int dP = min(T + 4, 158);
#pragma unroll
        for (int r = 0; r < 6; ++r) buf[r] = *(const float4*)(pS + dP * 1536 + r * 256);
    }
}

// ---------------- NW backward: 4-wave mailbox pipeline; publish path touches ONLY LDS ----------------
__global__ __launch_bounds__(256, 1) void nw_bwd_kernel(const float* __restrict__ simD,
                                                        const float* __restrict__ VD,
                                                        const int* __restrict__ shapes,
                                                        float* __restrict__ ED) {
    int b = blockIdx.x;
    int tid = threadIdx.x;
    int w = tid >> 6, l = tid & 63;
    __shared__ float4 MA[4][64], MB4[4][64], MC[4][64], MD[4][64], MEx[4][64], MF[4][64];
    __shared__ int FL[4];
    const float4 Z4 = {0.f, 0.f, 0.f, 0.f};
    {
        int s = tid >> 6, ll = tid & 63;
        MA[s][ll] = Z4; MB4[s][ll] = Z4; MC[s][ll] = Z4;
        MD[s][ll] = Z4; MEx[s][ll] = Z4; MF[s][ll] = Z4;
    }
    if (tid < 4) FL[tid] = (tid == 3) ? -1 : -1000000;
    __syncthreads();
    volatile int* flg = FL;
    const float* pS = simD + (size_t)b * SZD + l * 4;
    const float* pV = VD   + (size_t)b * SZD + l * 4;
    float*       pE = ED   + (size_t)b * SZD + l * 4;
    int li = min(max(shapes[2 * b + 0], 0), L_);
    int lj = min(max(shapes[2 * b + 1], 0), L_);
    float4 bufV[6], bufS[6];
#pragma unroll
    for (int r = 0; r < 6; ++r) {
        bufV[r] = *(const float4*)(pV + (158 - w) * 1536 + r * 256);
        bufS[r] = *(const float4*)(pS + (158 - w) * 1536 + r * 256);
    }
    int lp = (l == 63) ? 63 : (l + 1);
#pragma unroll 1
    for (int T = w; T < 159; T += 4) {
        int sp = (T - 1) & 3;
        while (flg[sp] != T - 1) {}
        asm volatile("" ::: "memory");
        float4 Ar = MA[sp][l];
        float4 Br = MB4[sp][l];
        float4 Cr = MC[sp][l];
        float4 Dn = MD[sp][lp];
        float4 En = MEx[sp][lp];
        float4 Fn = MF[sp][lp];
        if (l == 63) { Dn = Z4; En = Z4; Fn = Z4; }
        float einit[6] = {Ar.x, Ar.y, Ar.z, Ar.w, Br.x, Br.y};
        float uinit[6] = {Br.z, Br.w, Cr.x, Cr.y, Cr.z, Cr.w};
        float enb_c[4] = {Dn.x, Dn.y, Dn.z, Dn.w};   // E[6l+7, c0+1+q]
        float unb_c[4] = {En.x, En.y, En.z, En.w};   // U[6l+7, c0+1+q]
        float enbtd_s = Fn.x, unbtd_s = Fn.y;        // E/U[6l+7, rightmost+1]
        float Vq[6][4], Sq[6][4];
#pragma unroll
        for (int r = 0; r < 6; ++r) {
            Vq[r][0] = bufV[r].x; Vq[r][1] = bufV[r].y; Vq[r][2] = bufV[r].z; Vq[r][3] = bufV[r].w;
            Sq[r][0] = bufS[r].x; Sq[r][1] = bufS[r].y; Sq[r][2] = bufS[r].z; Sq[r][3] = bufS[r].w;
        }
        int ct = 158 - T - l;
        bool act = (ct >= 0 && ct <= 95);
        float necar[4] = {0.f, 0.f, 0.f, 0.f}, nucar[4] = {0.f, 0.f, 0.f, 0.f};
        float eC[6], uC[6];
#pragma unroll
        for (int r = 0; r < 6; ++r) { eC[r] = einit[r]; uC[r] = uinit[r]; }
        float Eo[6][4];
        if (act) {
            // ---- phase 1: all U values ----
            float Uo[6][4];
#pragma unroll
            for (int r = 0; r < 6; ++r)
#pragma unroll
                for (int q = 0; q < 4; ++q)
                    Uo[r][q] = Vq[r][q] - Sq[r][q];
            // ---- phase 2: all 72 exp-weights (independent of E-chain) ----
            float wtd[6][4], wtu[6][4], wtl[6][4];
#pragma unroll
            for (int r = 0; r < 6; ++r) {
                int i = 6 * l + r + 1;
                bool ilt = (i < L_);
#pragma unroll
                for (int q = 0; q < 4; ++q) {
                    int j = 4 * ct + q + 1;
                    bool jlt = (j < L_);
                    float ub_old = (r == 5) ? ((q == 3) ? unbtd_s : unb_c[q + 1])
                                            : ((q == 3) ? uinit[r + 1] : Uo[r + 1][q + 1]);
                    float ub_new = (r == 5) ? unb_c[q] : Uo[r + 1][q];
                    float uo_r   = (q == 3) ? uinit[r] : Uo[r][q + 1];
                    wtd[r][q] = (ilt && jlt) ? __expf(Vq[r][q] - ub_old) : 0.f;
                    wtu[r][q] = ilt ? __expf(Vq[r][q] - ub_new) : 0.f;
                    wtl[r][q] = jlt ? __expf(Vq[r][q] - uo_r) : 0.f;
                }
            }
            // ---- phase 3: E recurrence, mini-diagonal order ----
#pragma unroll
            for (int dd = 0; dd < 9; ++dd) {
#pragma unroll
                for (int r = 5; r >= 0; --r) {
                    const int q = 8 - dd - r;
                    if (q < 0 || q > 3) continue;
                    int i = 6 * l + r + 1;
                    int j = 4 * ct + q + 1;
                    float eb_old = (r == 5) ? ((q == 3) ? enbtd_s : enb_c[q + 1])
                                            : ((q == 3) ? einit[r + 1] : Eo[r + 1][q + 1]);
                    float eb_new = (r == 5) ? enb_c[q] : Eo[r + 1][q];
                    float eo_r   = (q == 3) ? einit[r] : Eo[r][q + 1];
                    float en = (i == li && j == lj) ? 1.f : 0.f;
                    en += wtd[r][q] * eb_old + wtu[r][q] * eb_new + wtl[r][q] * eo_r;
                    Eo[r][q] = en;
                }
            }
#pragma unroll
            for (int r = 0; r < 6; ++r) { eC[r] = Eo[r][0]; uC[r] = Uo[r][0]; }
#pragma unroll
            for (int q = 0; q < 4; ++q) { necar[q] = Eo[0][q]; nucar[q] = Uo[0][q]; }
        }
        // ---- publish (LDS only) ----
        float4 pa; pa.x = eC[0]; pa.y = eC[1]; pa.z = eC[2]; pa.w = eC[3];
        float4 pb; pb.x = eC[4]; pb.y = eC[5]; pb.z = uC[0]; pb.w = uC[1];
        float4 pc; pc.x = uC[2]; pc.y = uC[3]; pc.z = uC[4]; pc.w = uC[5];
        float4 pd; pd.x = necar[0]; pd.y = necar[1]; pd.z = necar[2]; pd.w = necar[3];
        float4 pe; pe.x = nucar[0]; pe.y = nucar[1]; pe.z = nucar[2]; pe.w = nucar[3];
        float4 pf; pf.x = einit[0]; pf.y = uinit[0]; pf.z = 0.f; pf.w = 0.f;
        MA[w][l] = pa; MB4[w][l] = pb; MC[w][l] = pc;
        MD[w][l] = pd; MEx[w][l] = pe; MF[w][l] = pf;
        asm volatile("s_waitcnt lgkmcnt(0)" ::: "memory");
        if (l == 0) flg[w] = T;
        asm volatile("" ::: "memory");
        // ---- global ops AFTER publish ----
        if (act) {
            float* pEd = pE + (size_t)(158 - T) * 1536;
#pragma unroll
            for (int r = 0; r < 6; ++r) {
                float4 t;
                t.x = Eo[r][0]; t.y = Eo[r][1]; t.z = Eo[r][2]; t.w = Eo[r][3];
                *(float4*)(pEd + r * 256) = t;
            }
        }
        int dP = max(158 - (T + 4), 0);
#pragma unroll
        for (int r = 0; r < 6; ++r) {
            bufV[r] = *(const float4*)(pV + dP * 1536 + r * 256);
            bufS[r] = *(const float4*)(pS + dP * 1536 + r * 256);
        }
    }
}

// ---------------- repack: EDiag (diag layout) -> Enat (B, L, L) row-major ----------------
__global__ __launch_bounds__(256) void repack_kernel(const float* __restrict__ ED,
                                                     float* __restrict__ Enat) {
    int n  = blockIdx.y;
    int jt = blockIdx.x;                 // 0..5
    int jl = threadIdx.x & 63;
    int gp = threadIdx.x >> 6;           // 0..3: i in [gp*96, gp*96+96)
    int j  = jt * 64 + jl;
    const float* eb = ED + (size_t)n * SZD + (j >> 2) * 1536 + (j & 3);
    float* ob = Enat + (size_t)n * LL + j;
#pragma unroll 4
    for (int i = gp * 96; i < gp * 96 + 96; ++i) {
        int dl = i / 6, dr = i - dl * 6;
        float v = eb[(size_t)dl * 1540 + dr * 256];   // dl*1536 + dl*4
        ob[(size_t)i * L_] = v;
    }
}

// ---------------- consensus[j,a] = (1/B) sum_n sum_i matrices[n,a,i]*E[n,i,j] ----------------
__global__ __launch_bounds__(256) void consensus_kernel(const float* __restrict__ x,      // (B,A,L)
                                                        const float* __restrict__ Enat,   // (B,L,L)
                                                        float* __restrict__ cons) {       // (L,A)
    int n  = blockIdx.y;
    int j0 = blockIdx.x * 64;
    __shared__ float ms[A_][L_];    // 39.9 KB: matrices[n] staged
    for (int idx = threadIdx.x; idx < A_ * L_; idx += 256)
        ((float*)ms)[idx] = x[(size_t)n * A_ * L_ + idx];
    __syncthreads();
    int jl = threadIdx.x & 63;
    int g  = threadIdx.x >> 6;      // 0..3
    int a0 = g * 7;                 // 0,7,14,21
    int na = (a0 + 7 <= A_) ? 7 : (A_ - a0);   // 7,7,7,5
    int j  = j0 + jl;
    float acc[7] = {0.f, 0.f, 0.f, 0.f, 0.f, 0.f, 0.f};
    const float* aE = Enat + (size_t)n * LL + j;
    for (int i = 0; i < L_; ++i) {
        float al = aE[(size_t)i * L_];
#pragma unroll
        for (int t = 0; t < 7; ++t)
            if (t < na) acc[t] = fmaf(al, ms[a0 + t][i], acc[t]);
    }
    for (int t = 0; t < na; ++t)
        atomicAdd(&cons[(size_t)j * A_ + a0 + t], acc[t] * (1.0f / B_));
}

// ---------------- out[n,i,a] = sum_j cons[j,a] * E[n,i,j] ----------------
__global__ __launch_bounds__(256) void out_kernel(const float* __restrict__ Enat,
                                                  const float* __restrict__ cons,
                                                  float* __restrict__ out) {
    int n  = blockIdx.y;
    int i0 = blockIdx.x * 32;
    __shared__ float cs[L_][A_];        // 40.0 KB
    __shared__ float as_[32][L_ + 1];   // 49.3 KB (pad: break 384-stride bank alias)
    for (int idx = threadIdx.x; idx < L_ * A_; idx += 256)
        ((float*)cs)[idx] = cons[idx];
    const float* aE = Enat + (size_t)n * LL;
    for (int idx = threadIdx.x; idx < 32 * L_; idx += 256) {
        int r = idx / L_, c = idx - r * L_;
        as_[r][c] = aE[(size_t)(i0 + r) * L_ + c];
    }
    __syncthreads();
    for (int o = threadIdx.x; o < 32 * A_; o += 256) {
        int il = o / A_, a = o % A_;
        float s = 0.f;
        for (int jj = 0; jj < L_; ++jj)
            s = fmaf(as_[il][jj], cs[jj][a], s);
        out[((size_t)n * L_ + i0 + il) * A_ + a] = s;
    }
}

extern "C" void kernel_launch(void* const* d_in, const int* in_sizes, int n_in,
                              void* d_out, int out_size, void* d_ws, size_t ws_size,
                              hipStream_t stream) {
    const float* matrices = (const float*)d_in[0];   // (B,A,L) f32
    const int*   shapes   = (const int*)d_in[1];     // (B,2) i32
    const float* conv_w   = (const float*)d_in[2];   // (D,A,K) f32
    const float* conv_b   = (const float*)d_in[3];   // (D,) f32
    float* out = (float*)d_out;                      // (B,L,A) f32

    char* p = (char*)d_ws;
    // region1 (62.9 MB): xcol hi/lo (47.2 MB) during conv; EDiag after bwd (xcol dead).
    float*    EDiag = (float*)p;
    ushort_t* xh = (ushort_t*)p;
    ushort_t* xl = xh + (size_t)B_ * 15 * L_ * 32;
    p += (size_t)B_ * SZD * 4;
    // region2 (50.3 MB): ehi/elo (dead after sim_kernel).
    ushort_t* ehi = (ushort_t*)p;
    ushort_t* elo = ehi + (size_t)B_ * 16 * L_ * 32;
    p += (size_t)B_ * L_ * D_ * 4;
    // region3 (62.9 MB): simD (dead after bwd) -> Enat (37.7 MB) for repack.
    float* simD = (float*)p;
    float* Enat = simD;
    p += (size_t)B_ * SZD * 4;
    // region4 (62.9 MB): VD.
    float* VD = (float*)p;
    p += (size_t)B_ * SZD * 4;
    ushort_t* wh = (ushort_t*)p;                     // 0.49 MB
    ushort_t* wl = wh + (size_t)15 * D_ * 32;        // 0.49 MB
    p += (size_t)15 * D_ * 32 * 4;
    float* cons = (float*)p;                         // 40 KB

    wsplit_kernel<<<(D_ * KC + 255) / 256, 256, 0, stream>>>(conv_w, wh, wl);
    im2col_kernel<<<dim3(L_ / 64, B_), 256, 0, stream>>>(matrices, xh, xl);
    convmm_kernel<<<dim3(D_ / 64, L_ / 64, B_), 256, 0, stream>>>(xh, xl, wh, wl, conv_b, ehi, elo);
    sim_kernel<<<dim3(L_ / 64, L_ / 64, B_), 256, 0, stream>>>(ehi, elo, simD);
    nw_fwd_kernel<<<B_, 256, 0, stream>>>(simD, VD);
    nw_bwd_kernel<<<B_, 256, 0, stream>>>(simD, VD, shapes, EDiag);
    repack_kernel<<<dim3(L_ / 64, B_), 256, 0, stream>>>(EDiag, Enat);
    hipMemsetAsync(cons, 0, (size_t)L_ * A_ * sizeof(float), stream);
    consensus_kernel<<<dim3(L_ / 64, B_), 256, 0, stream>>>(matrices, Enat, cons);
    out_kernel<<<dim3(L_ / 32, B_), 256, 0, stream>>>(Enat, cons, out);
}

// Round 17
// 900.829 us; speedup vs baseline: 1.1290x; 1.0334x over previous
//
#include <hip/hip_runtime.h>
#include <hip/hip_bf16.h>
#include <math.h>

#define B_  64
#define A_  26
#define L_  384
#define D_  512
#define K_  18
#define KC  480      // im2col K padded (468 -> 480, 15 slices of 32)
#define LL  147456   // L_*L_
#define SZD 245760   // per-batch diagonal-layout stride: 160 diags x 1536 floats

typedef __attribute__((ext_vector_type(8))) short bf16x8;   // 8 bf16 = 4 VGPRs
typedef __attribute__((ext_vector_type(4))) float f32x4;
typedef unsigned short ushort_t;
typedef unsigned int uint_t;

// Diagonal layout for sim/V/E matrices (NW-dense): element (row z, col c):
//   addr = (z/6 + c/4)*1536 + (z%6)*256 + (z/6)*4 + (c&3)
__device__ __forceinline__ void stD(float* sp, int z, int c, float v) {
    int dl = z / 6, dr = z - dl * 6;
    sp[(size_t)(dl + (c >> 2)) * 1536 + dr * 256 + dl * 4 + (c & 3)] = v;
}

// RNE f32 -> bf16 bits
__device__ __forceinline__ ushort_t f2bf(float v) {
    uint_t u = __float_as_uint(v);
    uint_t r = (u + 0x7FFFu + ((u >> 16) & 1u)) >> 16;
    return (ushort_t)r;
}

// ---------------- weight split: conv_w (D, A*K) -> k-major wcol hi/lo [ks][d][32] ----------------
__global__ void wsplit_kernel(const float* __restrict__ w, ushort_t* __restrict__ wh,
                              ushort_t* __restrict__ wl) {
    int o = blockIdx.x * blockDim.x + threadIdx.x;   // o = d*KC + r
    if (o >= D_ * KC) return;
    int d = o / KC, r = o - d * KC;
    float v = (r < A_ * K_) ? w[(size_t)d * (A_ * K_) + r] : 0.0f;
    ushort_t h = f2bf(v);
    float hf = __uint_as_float(((uint_t)h) << 16);
    size_t oo = ((size_t)(r >> 5) * D_ + d) * 32 + (r & 31);
    wh[oo] = h;
    wl[oo] = f2bf(v - hf);
}

// ---------------- im2col: x (B,A,L) -> k-major xcol hi/lo [b][ks][l][32] ----------------
__global__ __launch_bounds__(256) void im2col_kernel(const float* __restrict__ x,
                                                     ushort_t* __restrict__ xh,
                                                     ushort_t* __restrict__ xl) {
    int b  = blockIdx.y;
    int lt = blockIdx.x;                 // 0..5, 64 l's each
    const float* xb = x + (size_t)b * A_ * L_;
    for (int idx = threadIdx.x; idx < 64 * KC; idx += 256) {
        int l = lt * 64 + idx / KC;
        int r = idx % KC;
        float v = 0.0f;
        if (r < A_ * K_) {
            int a = r / K_, kk = r - a * K_;
            int g = l + kk - 8;
            if (g >= 0 && g < L_) v = xb[(size_t)a * L_ + g];
        }
        ushort_t h = f2bf(v);
        float hf = __uint_as_float(((uint_t)h) << 16);
        size_t o = (((size_t)b * 15 + (r >> 5)) * L_ + l) * 32 + (r & 31);
        xh[o] = h;
        xl[o] = f2bf(v - hf);
    }
}

// ---------------- conv as split-bf16 MFMA GEMM (k-major streams, dense loads) ----------------
__global__ __launch_bounds__(256) void convmm_kernel(const ushort_t* __restrict__ xh,
                                                     const ushort_t* __restrict__ xl,
                                                     const ushort_t* __restrict__ wh,
                                                     const ushort_t* __restrict__ wl,
                                                     const float* __restrict__ bias,
                                                     ushort_t* __restrict__ ehi,
                                                     ushort_t* __restrict__ elo) {
    int b = blockIdx.z;
    int w = threadIdx.x >> 6;
    int lane = threadIdx.x & 63;
    int l0 = blockIdx.y * 64 + 32 * (w >> 1);
    int d0 = blockIdx.x * 64 + 32 * (w & 1);
    int r = lane & 15, g = lane >> 4;
    const ushort_t* pah = xh + (((size_t)b * 15) * L_ + l0 + r) * 32 + g * 8;
    const ushort_t* pal = xl + (((size_t)b * 15) * L_ + l0 + r) * 32 + g * 8;
    const ushort_t* pbh = wh + (size_t)(d0 + r) * 32 + g * 8;
    const ushort_t* pbl = wl + (size_t)(d0 + r) * 32 + g * 8;
    f32x4 acc00 = {0.f, 0.f, 0.f, 0.f}, acc01 = acc00, acc10 = acc00, acc11 = acc00;
#pragma unroll 3
    for (int ks = 0; ks < 15; ++ks) {
        size_t offA = (size_t)ks * L_ * 32;
        size_t offB = (size_t)ks * D_ * 32;
        bf16x8 Ah0 = *(const bf16x8*)(pah + offA);
        bf16x8 Ah1 = *(const bf16x8*)(pah + offA + 16 * 32);
        bf16x8 Al0 = *(const bf16x8*)(pal + offA);
        bf16x8 Al1 = *(const bf16x8*)(pal + offA + 16 * 32);
        bf16x8 Bh0 = *(const bf16x8*)(pbh + offB);
        bf16x8 Bh1 = *(const bf16x8*)(pbh + offB + 16 * 32);
        bf16x8 Bl0 = *(const bf16x8*)(pbl + offB);
        bf16x8 Bl1 = *(const bf16x8*)(pbl + offB + 16 * 32);
        acc00 = __builtin_amdgcn_mfma_f32_16x16x32_bf16(Ah0, Bh0, acc00, 0, 0, 0);
        acc00 = __builtin_amdgcn_mfma_f32_16x16x32_bf16(Ah0, Bl0, acc00, 0, 0, 0);
        acc00 = __builtin_amdgcn_mfma_f32_16x16x32_bf16(Al0, Bh0, acc00, 0, 0, 0);
        acc01 = __builtin_amdgcn_mfma_f32_16x16x32_bf16(Ah0, Bh1, acc01, 0, 0, 0);
        acc01 = __builtin_amdgcn_mfma_f32_16x16x32_bf16(Ah0, Bl1, acc01, 0, 0, 0);
        acc01 = __builtin_amdgcn_mfma_f32_16x16x32_bf16(Al0, Bh1, acc01, 0, 0, 0);
        acc10 = __builtin_amdgcn_mfma_f32_16x16x32_bf16(Ah1, Bh0, acc10, 0, 0, 0);
        acc10 = __builtin_amdgcn_mfma_f32_16x16x32_bf16(Ah1, Bl0, acc10, 0, 0, 0);
        acc10 = __builtin_amdgcn_mfma_f32_16x16x32_bf16(Al1, Bh0, acc10, 0, 0, 0);
        acc11 = __builtin_amdgcn_mfma_f32_16x16x32_bf16(Ah1, Bh1, acc11, 0, 0, 0);
        acc11 = __builtin_amdgcn_mfma_f32_16x16x32_bf16(Ah1, Bl1, acc11, 0, 0, 0);
        acc11 = __builtin_amdgcn_mfma_f32_16x16x32_bf16(Al1, Bh1, acc11, 0, 0, 0);
    }
#pragma unroll
    for (int v = 0; v < 4; ++v) {
        int lr0 = l0 + g * 4 + v, lr1 = lr0 + 16;
        int dc0 = d0 + r,         dc1 = dc0 + 16;
        float vals[4] = {acc00[v] + bias[dc0], acc01[v] + bias[dc1],
                         acc10[v] + bias[dc0], acc11[v] + bias[dc1]};
        int lrs[4] = {lr0, lr0, lr1, lr1};
        int dcs[4] = {dc0, dc1, dc0, dc1};
#pragma unroll
        for (int t = 0; t < 4; ++t) {
            ushort_t h = f2bf(vals[t]);
            float hf = __uint_as_float(((uint_t)h) << 16);
            size_t o = (((size_t)b * 16 + (dcs[t] >> 5)) * L_ + lrs[t]) * 32 + (dcs[t] & 31);
            ehi[o] = h;
            elo[o] = f2bf(vals[t] - hf);
        }
    }
}

// ---------------- sim = E_b · E_0^T via split-bf16 MFMA (k-major streams); writes diag layout ----------------
__global__ __launch_bounds__(256) void sim_kernel(const ushort_t* __restrict__ ehi,
                                                  const ushort_t* __restrict__ elo,
                                                  float* __restrict__ simD) {
    int b = blockIdx.z;
    int w = threadIdx.x >> 6;
    int lane = threadIdx.x & 63;
    int l0 = blockIdx.y * 64 + 32 * (w >> 1);
    int m0 = blockIdx.x * 64 + 32 * (w & 1);
    int r = lane & 15, g = lane >> 4;
    const ushort_t* pah = ehi + (((size_t)b * 16) * L_ + l0 + r) * 32 + g * 8;
    const ushort_t* pal = elo + (((size_t)b * 16) * L_ + l0 + r) * 32 + g * 8;
    const ushort_t* pbh = ehi + ((size_t)(m0 + r)) * 32 + g * 8;   // batch 0
    const ushort_t* pbl = elo + ((size_t)(m0 + r)) * 32 + g * 8;
    f32x4 acc00 = {0.f, 0.f, 0.f, 0.f}, acc01 = acc00, acc10 = acc00, acc11 = acc00;
#pragma unroll 2
    for (int ks = 0; ks < 16; ++ks) {
        size_t off = (size_t)ks * L_ * 32;
        bf16x8 Ah0 = *(const bf16x8*)(pah + off);
        bf16x8 Ah1 = *(const bf16x8*)(pah + off + 16 * 32);
        bf16x8 Al0 = *(const bf16x8*)(pal + off);
        bf16x8 Al1 = *(const bf16x8*)(pal + off + 16 * 32);
        bf16x8 Bh0 = *(const bf16x8*)(pbh + off);
        bf16x8 Bh1 = *(const bf16x8*)(pbh + off + 16 * 32);
        bf16x8 Bl0 = *(const bf16x8*)(pbl + off);
        bf16x8 Bl1 = *(const bf16x8*)(pbl + off + 16 * 32);
        acc00 = __builtin_amdgcn_mfma_f32_16x16x32_bf16(Ah0, Bh0, acc00, 0, 0, 0);
        acc00 = __builtin_amdgcn_mfma_f32_16x16x32_bf16(Ah0, Bl0, acc00, 0, 0, 0);
        acc00 = __builtin_amdgcn_mfma_f32_16x16x32_bf16(Al0, Bh0, acc00, 0, 0, 0);
        acc01 = __builtin_amdgcn_mfma_f32_16x16x32_bf16(Ah0, Bh1, acc01, 0, 0, 0);
        acc01 = __builtin_amdgcn_mfma_f32_16x16x32_bf16(Ah0, Bl1, acc01, 0, 0, 0);
        acc01 = __builtin_amdgcn_mfma_f32_16x16x32_bf16(Al0, Bh1, acc01, 0, 0, 0);
        acc10 = __builtin_amdgcn_mfma_f32_16x16x32_bf16(Ah1, Bh0, acc10, 0, 0, 0);
        acc10 = __builtin_amdgcn_mfma_f32_16x16x32_bf16(Ah1, Bl0, acc10, 0, 0, 0);
        acc10 = __builtin_amdgcn_mfma_f32_16x16x32_bf16(Al1, Bh0, acc10, 0, 0, 0);
        acc11 = __builtin_amdgcn_mfma_f32_16x16x32_bf16(Ah1, Bh1, acc11, 0, 0, 0);
        acc11 = __builtin_amdgcn_mfma_f32_16x16x32_bf16(Ah1, Bl1, acc11, 0, 0, 0);
        acc11 = __builtin_amdgcn_mfma_f32_16x16x32_bf16(Al1, Bh1, acc11, 0, 0, 0);
    }
    float* sp = simD + (size_t)b * SZD;
#pragma unroll
    for (int v = 0; v < 4; ++v) {
        int ar0 = l0 + g * 4 + v, ar1 = ar0 + 16;
        int ac0 = m0 + r,         ac1 = ac0 + 16;
        stD(sp, ar0, ac0, acc00[v]);
        stD(sp, ar0, ac1, acc01[v]);
        stD(sp, ar1, ac0, acc10[v]);
        stD(sp, ar1, ac1, acc11[v]);
    }
}

// ---------------- NW forward: 4-wave mailbox pipeline, med3 smoothmax (3 trans/cell) ----------------
// V[i,j] = sim[i-1,j-1] + mx + log(1 + exp(med-mx) + exp(min-mx))   (exp(mx-mx)=1 free)
__global__ __launch_bounds__(256, 1) void nw_fwd_kernel(const float* __restrict__ simD, float* __restrict__ VD) {
    int b = blockIdx.x;
    int tid = threadIdx.x;
    int w = tid >> 6, l = tid & 63;
    __shared__ float4 MA[4][64], MB4[4][64], MC[4][64];
    __shared__ int FL[4];
    const float4 Z4 = {0.f, 0.f, 0.f, 0.f};
    {
        int s = tid >> 6, ll = tid & 63;
        MA[s][ll] = Z4; MB4[s][ll] = Z4; MC[s][ll] = Z4;
    }
    if (tid < 4) FL[tid] = (tid == 3) ? -1 : -1000000;
    __syncthreads();
    volatile int* flg = FL;
    const float* pS = simD + (size_t)b * SZD + l * 4;
    float*       pV = VD   + (size_t)b * SZD + l * 4;
    float4 buf[6];
#pragma unroll
    for (int r = 0; r < 6; ++r) buf[r] = *(const float4*)(pS + w * 1536 + r * 256);
    int lm = (l == 0) ? 0 : (l - 1);
#pragma unroll 1
    for (int T = w; T < 159; T += 4) {
        int sp = (T - 1) & 3;
        while (flg[sp] != T - 1) {}
        asm volatile("" ::: "memory");
        float4 Ar = MA[sp][l];
        float4 Bs = MB4[sp][l];
        float4 Cs = MC[sp][l];
        float4 Bn = MB4[sp][lm];
        float4 Cn = MC[sp][lm];
        if (l == 0) { Bn = Z4; Cn = Z4; }
        float vleft[6] = {Ar.x, Ar.y, Ar.z, Ar.w, Bs.x, Bs.y};
        float d0 = Bn.z;                              // V[6l, c0]
        float uin[4] = {Cn.x, Cn.y, Cn.z, Cn.w};      // V[6l, c0+q+1]
        float sc[6][4];
#pragma unroll
        for (int r = 0; r < 6; ++r) {
            sc[r][0] = buf[r].x; sc[r][1] = buf[r].y; sc[r][2] = buf[r].z; sc[r][3] = buf[r].w;
        }
        int ct = T - l;
        bool act = (ct >= 0 && ct <= 95);
        float nbc[4] = {0.f, 0.f, 0.f, 0.f}, nbp = 0.f;
        float vout[6][4];
        if (act) {
#pragma unroll
            for (int dd = 0; dd < 9; ++dd) {
#pragma unroll
                for (int r = 0; r < 6; ++r) {
                    const int q = dd - r;
                    if (q < 0 || q > 3) continue;
                    float dg = (r == 0) ? ((q == 0) ? d0 : uin[q - 1])
                                        : ((q == 0) ? vleft[r - 1] : vout[r - 1][q - 1]);
                    float up = (r == 0) ? uin[q] : vout[r - 1][q];
                    float lf = (q == 0) ? vleft[r] : vout[r][q - 1];
                    float mx = fmaxf(dg, fmaxf(up, lf));
                    float mn = fminf(dg, fminf(up, lf));
                    float md = __builtin_amdgcn_fmed3f(dg, up, lf);
                    vout[r][q] = sc[r][q] + mx +
                        __logf(1.0f + (__expf(md - mx) + __expf(mn - mx)));
                }
            }
            nbp = Cs.w;                               // own old bcarry[3] = V[6l+6, 4ct]
#pragma unroll
            for (int q = 0; q < 4; ++q) nbc[q] = vout[5][q];
#pragma unroll
            for (int r = 0; r < 6; ++r) vleft[r] = vout[r][3];
        }
        // ---- publish (LDS only) ----
        float4 pa; pa.x = vleft[0]; pa.y = vleft[1]; pa.z = vleft[2]; pa.w = vleft[3];
        float4 pb; pb.x = vleft[4]; pb.y = vleft[5]; pb.z = nbp; pb.w = 0.f;
        float4 pc; pc.x = nbc[0]; pc.y = nbc[1]; pc.z = nbc[2]; pc.w = nbc[3];
        MA[w][l] = pa; MB4[w][l] = pb; MC[w][l] = pc;
        asm volatile("s_waitcnt lgkmcnt(0)" ::: "memory");
        if (l == 0) flg[w] = T;
        asm volatile("" ::: "memory");
        // ---- global ops AFTER publish ----
        if (act) {
            float* pVd = pV + (size_t)T * 1536;
#pragma unroll
            for (int r = 0; r < 6; ++r) {
                float4 t;
                t.x = vout[r][0]; t.y = vout[r][1]; t.z = vout[r][2]; t.w = vout[r][3];
                *(float4*)(pVd + r * 256) = t;
            }
        }
        int dP = min(T + 4, 158);
#pragma unroll
        for (int r = 0; r < 6; ++r) buf[r] = *(const float4*)(pS + dP * 1536 + r * 256);
    }
}

// ---------------- NW backward: exp-weights HOISTED out of the serial chain ----------------
// All U values (= V - S, pure input function) and all 72 exp-weights are computed
// BEFORE the flag poll (overlapping other waves' chain work on other SIMDs).
// Post-poll: only the 3-FMA/cell E-recurrence (path 9) + LDS mailbox handoff.
// Former mailbox-carried U values reloaded from diag+1/diag+2 (dense, bit-identical).
__global__ __launch_bounds__(256, 1) void nw_bwd_kernel(const float* __restrict__ simD,
                                                        const float* __restrict__ VD,
                                                        const int* __restrict__ shapes,
                                                        float* __restrict__ ED) {
    int b = blockIdx.x;
    int tid = threadIdx.x;
    int w = tid >> 6, l = tid & 63;
    __shared__ float4 MA[4][64], MB4[4][64], MD[4][64], MF[4][64];
    __shared__ int FL[4];
    const float4 Z4 = {0.f, 0.f, 0.f, 0.f};
    {
        int s = tid >> 6, ll = tid & 63;
        MA[s][ll] = Z4; MB4[s][ll] = Z4; MD[s][ll] = Z4; MF[s][ll] = Z4;
    }
    if (tid < 4) FL[tid] = (tid == 3) ? -1 : -1000000;
    __syncthreads();
    volatile int* flg = FL;
    const float* pS  = simD + (size_t)b * SZD + l * 4;
    const float* pV  = VD   + (size_t)b * SZD + l * 4;
    const float* pSn = simD + (size_t)b * SZD + (l + 1) * 4;   // neighbor row 6l+7 (dr=0, dl=l+1)
    const float* pVn = VD   + (size_t)b * SZD + (l + 1) * 4;
    float*       pE  = ED   + (size_t)b * SZD + l * 4;
    int li = min(max(shapes[2 * b + 0], 0), L_);
    int lj = min(max(shapes[2 * b + 1], 0), L_);
    float4 bufV[6], bufS[6], bufV2, bufS2;
    float bufV1x[6], bufS1x[6], bufV2bx, bufS2bx;
    {
        int dp = 158 - w;
#pragma unroll
        for (int r = 0; r < 6; ++r) {
            bufV[r] = *(const float4*)(pV + dp * 1536 + r * 256);
            bufS[r] = *(const float4*)(pS + dp * 1536 + r * 256);
            bufV1x[r] = *(pV + (dp + 1) * 1536 + r * 256);
            bufS1x[r] = *(pS + (dp + 1) * 1536 + r * 256);
        }
        bufV2 = *(const float4*)(pVn + (dp + 1) * 1536);
        bufS2 = *(const float4*)(pSn + (dp + 1) * 1536);
        bufV2bx = *(pVn + (dp + 2) * 1536 - 1536);   // clamp: use dp+1 region if would OOB? safe read anyway
        bufV2bx = *(pVn + min(dp + 2, 159) * 1536);
        bufS2bx = *(pSn + min(dp + 2, 159) * 1536);
    }
    int lp = (l == 63) ? 63 : (l + 1);
#pragma unroll 1
    for (int T = w; T < 159; T += 4) {
        int ct = 158 - T - l;
        bool act = (ct >= 0 && ct <= 95);
        // ======== PRE-POLL: unpack + all U + all 72 weights + deltas ========
        float Vq[6][4], Sq[6][4];
#pragma unroll
        for (int r = 0; r < 6; ++r) {
            Vq[r][0] = bufV[r].x; Vq[r][1] = bufV[r].y; Vq[r][2] = bufV[r].z; Vq[r][3] = bufV[r].w;
            Sq[r][0] = bufS[r].x; Sq[r][1] = bufS[r].y; Sq[r][2] = bufS[r].z; Sq[r][3] = bufS[r].w;
        }
        float uin1[6];
#pragma unroll
        for (int r = 0; r < 6; ++r) uin1[r] = bufV1x[r] - bufS1x[r];   // U[i, 4ct+5]
        float U2[4] = {bufV2.x - bufS2.x, bufV2.y - bufS2.y,
                       bufV2.z - bufS2.z, bufV2.w - bufS2.w};           // U[6l+7, 4ct+q+1]
        float u2s = bufV2bx - bufS2bx;                                  // U[6l+7, 4ct+5]
        float Uo[6][4];
#pragma unroll
        for (int r = 0; r < 6; ++r)
#pragma unroll
            for (int q = 0; q < 4; ++q)
                Uo[r][q] = Vq[r][q] - Sq[r][q];
        float wtd[6][4], wtu[6][4], wtl[6][4], del[6][4];
#pragma unroll
        for (int r = 0; r < 6; ++r) {
            int i = 6 * l + r + 1;
            bool ilt = (i < L_);
#pragma unroll
            for (int q = 0; q < 4; ++q) {
                int j = 4 * ct + q + 1;
                bool jlt = (j < L_);
                float ub_old = (r == 5) ? ((q == 3) ? u2s : U2[q + 1])
                                        : ((q == 3) ? uin1[r + 1] : Uo[r + 1][q + 1]);
                float ub_new = (r == 5) ? U2[q] : Uo[r + 1][q];
                float uo_r   = (q == 3) ? uin1[r] : Uo[r][q + 1];
                wtd[r][q] = (ilt && jlt) ? __expf(Vq[r][q] - ub_old) : 0.f;
                wtu[r][q] = ilt ? __expf(Vq[r][q] - ub_new) : 0.f;
                wtl[r][q] = jlt ? __expf(Vq[r][q] - uo_r) : 0.f;
                del[r][q] = (i == li && j == lj) ? 1.f : 0.f;
            }
        }
        __builtin_amdgcn_sched_barrier(0);
        // ======== POLL ========
        int sp = (T - 1) & 3;
        while (flg[sp] != T - 1) {}
        asm volatile("" ::: "memory");
        float4 Ar = MA[sp][l];
        float4 Br = MB4[sp][l];
        float4 Dn = MD[sp][lp];
        float4 Fn = MF[sp][lp];
        if (l == 63) { Dn = Z4; Fn = Z4; }
        float einit[6] = {Ar.x, Ar.y, Ar.z, Ar.w, Br.x, Br.y};
        float enb_c[4] = {Dn.x, Dn.y, Dn.z, Dn.w};   // E[6l+7, c0+1+q]
        float enbtd_s = Fn.x;                        // E[6l+7, rightmost+1]
        // ======== CHAIN: pure FMA E-recurrence, path 9 ========
        float necar[4] = {0.f, 0.f, 0.f, 0.f};
        float eC[6];
#pragma unroll
        for (int r = 0; r < 6; ++r) eC[r] = einit[r];
        float Eo[6][4];
        if (act) {
#pragma unroll
            for (int dd = 0; dd < 9; ++dd) {
#pragma unroll
                for (int r = 5; r >= 0; --r) {
                    const int q = 8 - dd - r;
                    if (q < 0 || q > 3) continue;
                    float eb_old = (r == 5) ? ((q == 3) ? enbtd_s : enb_c[q + 1])
                                            : ((q == 3) ? einit[r + 1] : Eo[r + 1][q + 1]);
                    float eb_new = (r == 5) ? enb_c[q] : Eo[r + 1][q];
                    float eo_r   = (q == 3) ? einit[r] : Eo[r][q + 1];
                    float en = del[r][q];
                    en += wtd[r][q] * eb_old + wtu[r][q] * eb_new + wtl[r][q] * eo_r;
                    Eo[r][q] = en;
                }
            }
#pragma unroll
            for (int r = 0; r < 6; ++r) eC[r] = Eo[r][0];
#pragma unroll
            for (int q = 0; q < 4; ++q) necar[q] = Eo[0][q];
        }
        // ======== PUBLISH (LDS only) ========
        float4 pa; pa.x = eC[0]; pa.y = eC[1]; pa.z = eC[2]; pa.w = eC[3];
        float4 pb; pb.x = eC[4]; pb.y = eC[5]; pb.z = 0.f; pb.w = 0.f;
        float4 pd; pd.x = necar[0]; pd.y = necar[1]; pd.z = necar[2]; pd.w = necar[3];
        float4 pf; pf.x = einit[0]; pf.y = 0.f; pf.z = 0.f; pf.w = 0.f;
        MA[w][l] = pa; MB4[w][l] = pb; MD[w][l] = pd; MF[w][l] = pf;
        asm volatile("s_waitcnt lgkmcnt(0)" ::: "memory");
        if (l == 0) flg[w] = T;
        asm volatile("" ::: "memory");
        // ======== global stores + prefetch for T+4 ========
        if (act) {
            float* pEd = pE + (size_t)(158 - T) * 1536;
#pragma unroll
            for (int r = 0; r < 6; ++r) {
                float4 t;
                t.x = Eo[r][0]; t.y = Eo[r][1]; t.z = Eo[r][2]; t.w = Eo[r][3];
                *(float4*)(pEd + r * 256) = t;
            }
        }
        int dp = max(158 - (T + 4), 0);
#pragma unroll
        for (int r = 0; r < 6; ++r) {
            bufV[r] = *(const float4*)(pV + dp * 1536 + r * 256);
            bufS[r] = *(const float4*)(pS + dp * 1536 + r * 256);
            bufV1x[r] = *(pV + (dp + 1) * 1536 + r * 256);
            bufS1x[r] = *(pS + (dp + 1) * 1536 + r * 256);
        }
        bufV2 = *(const float4*)(pVn + (dp + 1) * 1536);
        bufS2 = *(const float4*)(pSn + (dp + 1) * 1536);
        bufV2bx = *(pVn + min(dp + 2, 159) * 1536);
        bufS2bx = *(pSn + min(dp + 2, 159) * 1536);
    }
}

// ---------------- repack: EDiag (diag layout) -> Enat (B, L, L) row-major ----------------
__global__ __launch_bounds__(256) void repack_kernel(const float* __restrict__ ED,
                                                     float* __restrict__ Enat) {
    int n  = blockIdx.y;
    int jt = blockIdx.x;                 // 0..5
    int jl = threadIdx.x & 63;
    int gp = threadIdx.x >> 6;           // 0..3: i in [gp*96, gp*96+96)
    int j  = jt * 64 + jl;
    const float* eb = ED + (size_t)n * SZD + (j >> 2) * 1536 + (j & 3);
    float* ob = Enat + (size_t)n * LL + j;
#pragma unroll 4
    for (int i = gp * 96; i < gp * 96 + 96; ++i) {
        int dl = i / 6, dr = i - dl * 6;
        float v = eb[(size_t)dl * 1540 + dr * 256];   // dl*1536 + dl*4
        ob[(size_t)i * L_] = v;
    }
}

// ---------------- consensus[j,a] = (1/B) sum_n sum_i matrices[n,a,i]*E[n,i,j] ----------------
__global__ __launch_bounds__(256) void consensus_kernel(const float* __restrict__ x,      // (B,A,L)
                                                        const float* __restrict__ Enat,   // (B,L,L)
                                                        float* __restrict__ cons) {       // (L,A)
    int n  = blockIdx.y;
    int j0 = blockIdx.x * 64;
    __shared__ float ms[A_][L_];    // 39.9 KB: matrices[n] staged
    for (int idx = threadIdx.x; idx < A_ * L_; idx += 256)
        ((float*)ms)[idx] = x[(size_t)n * A_ * L_ + idx];
    __syncthreads();
    int jl = threadIdx.x & 63;
    int g  = threadIdx.x >> 6;      // 0..3
    int a0 = g * 7;                 // 0,7,14,21
    int na = (a0 + 7 <= A_) ? 7 : (A_ - a0);   // 7,7,7,5
    int j  = j0 + jl;
    float acc[7] = {0.f, 0.f, 0.f, 0.f, 0.f, 0.f, 0.f};
    const float* aE = Enat + (size_t)n * LL + j;
    for (int i = 0; i < L_; ++i) {
        float al = aE[(size_t)i * L_];
#pragma unroll
        for (int t = 0; t < 7; ++t)
            if (t < na) acc[t] = fmaf(al, ms[a0 + t][i], acc[t]);
    }
    for (int t = 0; t < na; ++t)
        atomicAdd(&cons[(size_t)j * A_ + a0 + t], acc[t] * (1.0f / B_));
}

// ---------------- out[n,i,a] = sum_j cons[j,a] * E[n,i,j] ----------------
__global__ __launch_bounds__(256) void out_kernel(const float* __restrict__ Enat,
                                                  const float* __restrict__ cons,
                                                  float* __restrict__ out) {
    int n  = blockIdx.y;
    int i0 = blockIdx.x * 32;
    __shared__ float cs[L_][A_];        // 40.0 KB
    __shared__ float as_[32][L_ + 1];   // 49.3 KB (pad: break 384-stride bank alias)
    for (int idx = threadIdx.x; idx < L_ * A_; idx += 256)
        ((float*)cs)[idx] = cons[idx];
    const float* aE = Enat + (size_t)n * LL;
    for (int idx = threadIdx.x; idx < 32 * L_; idx += 256) {
        int r = idx / L_, c = idx - r * L_;
        as_[r][c] = aE[(size_t)(i0 + r) * L_ + c];
    }
    __syncthreads();
    for (int o = threadIdx.x; o < 32 * A_; o += 256) {
        int il = o / A_, a = o % A_;
        float s = 0.f;
        for (int jj = 0; jj < L_; ++jj)
            s = fmaf(as_[il][jj], cs[jj][a], s);
        out[((size_t)n * L_ + i0 + il) * A_ + a] = s;
    }
}

extern "C" void kernel_launch(void* const* d_in, const int* in_sizes, int n_in,
                              void* d_out, int out_size, void* d_ws, size_t ws_size,
                              hipStream_t stream) {
    const float* matrices = (const float*)d_in[0];   // (B,A,L) f32
    const int*   shapes   = (const int*)d_in[1];     // (B,2) i32
    const float* conv_w   = (const float*)d_in[2];   // (D,A,K) f32
    const float* conv_b   = (const float*)d_in[3];   // (D,) f32
    float* out = (float*)d_out;                      // (B,L,A) f32

    char* p = (char*)d_ws;
    // region1 (62.9 MB): xcol hi/lo (47.2 MB) during conv; EDiag after bwd (xcol dead).
    float*    EDiag = (float*)p;
    ushort_t* xh = (ushort_t*)p;
    ushort_t* xl = xh + (size_t)B_ * 15 * L_ * 32;
    p += (size_t)B_ * SZD * 4;
    // region2 (50.3 MB): ehi/elo (dead after sim_kernel).
    ushort_t* ehi = (ushort_t*)p;
    ushort_t* elo = ehi + (size_t)B_ * 16 * L_ * 32;
    p += (size_t)B_ * L_ * D_ * 4;
    // region3 (62.9 MB): simD (dead after bwd) -> Enat (37.7 MB) for repack.
    float* simD = (float*)p;
    float* Enat = simD;
    p += (size_t)B_ * SZD * 4;
    // region4 (62.9 MB): VD.
    float* VD = (float*)p;
    p += (size_t)B_ * SZD * 4;
    ushort_t* wh = (ushort_t*)p;                     // 0.49 MB
    ushort_t* wl = wh + (size_t)15 * D_ * 32;        // 0.49 MB
    p += (size_t)15 * D_ * 32 * 4;
    float* cons = (float*)p;                         // 40 KB

    wsplit_kernel<<<(D_ * KC + 255) / 256, 256, 0, stream>>>(conv_w, wh, wl);
    im2col_kernel<<<dim3(L_ / 64, B_), 256, 0, stream>>>(matrices, xh, xl);
    convmm_kernel<<<dim3(D_ / 64, L_ / 64, B_), 256, 0, stream>>>(xh, xl, wh, wl, conv_b, ehi, elo);
    sim_kernel<<<dim3(L_ / 64, L_ / 64, B_), 256, 0, stream>>>(ehi, elo, simD);
    nw_fwd_kernel<<<B_, 256, 0, stream>>>(simD, VD);
    nw_bwd_kernel<<<B_, 256, 0, stream>>>(simD, VD, shapes, EDiag);
    repack_kernel<<<dim3(L_ / 64, B_), 256, 0, stream>>>(EDiag, Enat);
    hipMemsetAsync(cons, 0, (size_t)L_ * A_ * sizeof(float), stream);
    consensus_kernel<<<dim3(L_ / 64, B_), 256, 0, stream>>>(matrices, Enat, cons);
    out_kernel<<<dim3(L_ / 32, B_), 256, 0, stream>>>(Enat, cons, out);
}